// Round 15
// baseline (605.470 us; speedup 1.0000x reference)
//
#include <hip/hip_runtime.h>

#define N_NODES 100000
#define N_EDGES 1600000
#define N_GRAPHS 512
#define DH 128
#define CAP 64             // per-node edge capacity in scratch (max in-deg ~42)
#define NLAYERS 6
#define NBUCK 196          // buckets of 512 nodes
#define BCAP 8960          // per-bucket edge capacity (mean 8163, +8 sigma)
#define CHUNK_A 4096
#define BLOCKS_A ((N_EDGES + CHUNK_A - 1) / CHUNK_A)   // 391
#define SENT_OFF (N_NODES << 8)      // sentinel byte-offset -> zero row at N_NODES
#define NT_TILES (N_NODES / 16)      // 6250

typedef short bf16x8 __attribute__((ext_vector_type(8)));
typedef float f32x4 __attribute__((ext_vector_type(4)));

// ---- bf16 helpers (RNE) ----
__device__ inline unsigned int pk_bf16x2(float a, float b) {
    unsigned int ua = __float_as_uint(a), ub = __float_as_uint(b);
    ua += 0x7fffu + ((ua >> 16) & 1u);
    ub += 0x7fffu + ((ub >> 16) & 1u);
    return (ua >> 16) | (ub & 0xffff0000u);
}
__device__ inline unsigned short bf16_rne(float f) {
    unsigned int u = __float_as_uint(f);
    u += 0x7fffu + ((u >> 16) & 1u);
    return (unsigned short)(u >> 16);
}
__device__ inline float bf_lo(unsigned int u) { return __uint_as_float(u << 16); }
__device__ inline float bf_hi(unsigned int u) { return __uint_as_float(u & 0xffff0000u); }

// ---- Pass A: radix partition edges into NBUCK buckets (by dst>>9), packed ----
// entry = (src << 9) | (dst & 511)
__global__ __launch_bounds__(256) void binA_kernel(const int* __restrict__ src,
                                                   const int* __restrict__ dst,
                                                   int* __restrict__ bcur,
                                                   int* __restrict__ part) {
    __shared__ int hist[NBUCK];
    __shared__ int base[NBUCK];
    int tid = threadIdx.x;
    int e0 = blockIdx.x * CHUNK_A;
    int myE = N_EDGES - e0; if (myE > CHUNK_A) myE = CHUNK_A;
    for (int b = tid; b < NBUCK; b += 256) hist[b] = 0;
    __syncthreads();
    for (int i = tid; i < myE; i += 256) {
        int d = dst[e0 + i];
        atomicAdd(&hist[d >> 9], 1);
    }
    __syncthreads();
    for (int b = tid; b < NBUCK; b += 256) {
        base[b] = atomicAdd(&bcur[b], hist[b]);
        hist[b] = 0;                      // reuse as local cursor
    }
    __syncthreads();
    for (int i = tid; i < myE; i += 256) {
        int s = src[e0 + i], d = dst[e0 + i];
        int b = d >> 9;
        int off = atomicAdd(&hist[b], 1);
        int pos = base[b] + off;
        if (pos < BCAP) part[(size_t)b * BCAP + pos] = (s << 9) | (d & 511);
    }
}

// ---- Pass B: scatter into CAP-padded scratch (entries = src<<8 byte offsets),
// then repack into DENSE per-node stream padded to round16(deg) with sentinels.
// ninfo[n] = {dense base, round16(deg)}.
__global__ __launch_bounds__(256) void binB_kernel(const int* __restrict__ part,
                                                   const int* __restrict__ bcur,
                                                   int* __restrict__ cnt,
                                                   int* __restrict__ scratch,
                                                   int2* __restrict__ ninfo,
                                                   int* __restrict__ gcursor,
                                                   int* __restrict__ dense) {
    __shared__ int lcnt[512];
    __shared__ int nbase[512];
    __shared__ int psum[64];
    __shared__ int bucket_base;
    int tid = threadIdx.x;
    int b = blockIdx.x;
    int node0 = b << 9;
    for (int i = tid; i < 512; i += 256) lcnt[i] = 0;
    __syncthreads();
    int m = bcur[b]; if (m > BCAP) m = BCAP;
    const int* p = part + (size_t)b * BCAP;
    for (int i = tid; i < m; i += 256) {
        int v = p[i];
        int dl = v & 511;
        int sv = (int)(((unsigned int)v) >> 9);
        int r = atomicAdd(&lcnt[dl], 1);
        if (r < CAP) scratch[(size_t)(node0 + dl) * CAP + r] = sv << 8;
    }
    __syncthreads();
    for (int i = tid; i < 512; i += 256) {
        int n = node0 + i;
        if (n < N_NODES) cnt[n] = lcnt[i];
    }
    if (tid < 64) {
        int acc = 0;
        int base = tid * 8;
#pragma unroll
        for (int i = 0; i < 8; ++i) {
            int dg = lcnt[base + i]; if (dg > CAP) dg = CAP;
            acc += (dg + 15) & ~15;
        }
        psum[tid] = acc;
    }
    __syncthreads();
    if (tid == 0) {
        int acc = 0;
        for (int i = 0; i < 64; ++i) { int t = psum[i]; psum[i] = acc; acc += t; }
        bucket_base = atomicAdd(gcursor, acc);
    }
    __syncthreads();
    if (tid < 64) {
        int off = psum[tid];
        int base = tid * 8;
#pragma unroll
        for (int i = 0; i < 8; ++i) {
            int dg = lcnt[base + i]; if (dg > CAP) dg = CAP;
            nbase[base + i] = off;
            off += (dg + 15) & ~15;
        }
    }
    __syncthreads();
    int bb = bucket_base;
    for (int i = tid; i < 512; i += 256) {
        int n = node0 + i;
        if (n < N_NODES) {
            int dg = lcnt[i]; if (dg > CAP) dg = CAP;
            ninfo[n] = make_int2(bb + nbase[i], (dg + 15) & ~15);
        }
    }
    // repack: 32 nodes per round, 8 threads per node
    for (int nb = 0; nb < 512; nb += 32) {
        int nl = nb + (tid >> 3);
        int n = node0 + nl;
        if (n < N_NODES) {
            int dg = lcnt[nl]; if (dg > CAP) dg = CAP;
            int r16 = (dg + 15) & ~15;
            int* dst = dense + bb + nbase[nl];
            for (int e = tid & 7; e < r16; e += 8)
                dst[e] = (e < dg) ? scratch[(size_t)n * CAP + e] : SENT_OFF;
        }
    }
}

// ---- fused prep: dinv + sentinel-row zero + graph boundaries ----
__global__ void prep_kernel(const int* __restrict__ cnt, float* __restrict__ dinv,
                            unsigned int* __restrict__ hsb,
                            const int* __restrict__ batch, int* __restrict__ gptr) {
    int n = blockIdx.x * 256 + threadIdx.x;
    if (n < 64) hsb[(size_t)N_NODES * 64 + n] = 0u;
    if (n >= N_NODES) return;
    dinv[n] = rsqrtf((float)(cnt[n] + 1));
    int b1 = batch[n];
    if (n == 0) {
        for (int g = 0; g <= b1; ++g) gptr[g] = 0;
    } else {
        int b0 = batch[n - 1];
        for (int g = b0 + 1; g <= b1; ++g) gptr[g] = n;
    }
    if (n == N_NODES - 1) {
        for (int g = b1 + 1; g <= N_GRAPHS; ++g) gptr[g] = N_NODES;
    }
}

// ---- W split: WThi/WTlo[l][c][k] = hi/lo bf16 of W_l[k][c] (transposed) ----
__global__ void wsplit_kernel(const float* __restrict__ w0, const float* __restrict__ ws,
                              unsigned short* __restrict__ wthi,
                              unsigned short* __restrict__ wtlo) {
    int i = blockIdx.x * 256 + threadIdx.x;
    if (i >= NLAYERS * DH * DH) return;
    int l = i >> 14;
    int r = i & 16383;
    int c = r >> 7, k = r & 127;
    const float* W = (l == 0) ? w0 : ws + (size_t)(l - 1) * DH * DH;
    float f = W[k * DH + c];
    unsigned short hi = bf16_rne(f);
    float hif = __uint_as_float(((unsigned int)hi) << 16);
    unsigned short lo = bf16_rne(f - hif);
    wthi[i] = hi;
    wtlo[i] = lo;
}

// ---- x fp32 -> packed bf16x2, SLICE-MAJOR xb: xb[(cu>>3)*N + node][cu&7] ----
__global__ void xconv_kernel(const float* __restrict__ x, unsigned int* __restrict__ xb) {
    int i = blockIdx.x * 256 + threadIdx.x;       // one uint2 (4 floats) per thread
    if (i >= N_NODES * 32) return;
    float4 v = *(const float4*)&x[(size_t)i * 4];
    int node = i >> 5;
    int cu = (i & 31) * 2;
    int ss = cu >> 3, o = cu & 7;
    uint2 ov = make_uint2(pk_bf16x2(v.x, v.y), pk_bf16x2(v.z, v.w));
    *(uint2*)&xb[((size_t)ss * N_NODES + node) * 8 + o] = ov;
}

// ---- MFMA GEMM: sliced B-loads (coalesced), ROW-MAJOR stores to hsb ----
// block = 512 thr (8 waves); wave w owns output u32-cols [w*8, w*8+8).
#define LOADB(v, kb, nd) \
    v = *(const bf16x8*)&Xb[(((size_t)(2*(kb) + (lk >> 1)) * N_NODES + (nd)) * 8) + (lk & 1) * 4];

__global__ __launch_bounds__(512) void mfma_gemm_kernel(const unsigned int* __restrict__ Xb,
                                                        const unsigned short* __restrict__ WThi,
                                                        const unsigned short* __restrict__ WTlo,
                                                        const float* __restrict__ dinv,
                                                        unsigned int* __restrict__ Yb) {
    int w = threadIdx.x >> 6;
    int lane = threadIdx.x & 63;
    int l15 = lane & 15, lk = lane >> 4;          // lk in 0..3
    int wc = w * 16 + l15;                        // A row (output dim)
    bf16x8 ahi[4], alo[4];
#pragma unroll
    for (int kb = 0; kb < 4; ++kb) {
        int k0 = kb * 32 + lk * 8;
        ahi[kb] = *(const bf16x8*)&WThi[wc * DH + k0];
        alo[kb] = *(const bf16x8*)&WTlo[wc * DH + k0];
    }
    int nt = blockIdx.x;
    if (nt >= NT_TILES) return;
    int node = nt * 16 + l15;
    bf16x8 b0, b1, b2, b3;
    LOADB(b0, 0, node); LOADB(b1, 1, node); LOADB(b2, 2, node); LOADB(b3, 3, node);
    for (;;) {
        int ntn = nt + gridDim.x;
        bool hn = ntn < NT_TILES;
        int noden = ntn * 16 + l15;
        bf16x8 n0 = b0, n1 = b1, n2 = b2, n3 = b3;
        if (hn) { LOADB(n0, 0, noden); LOADB(n1, 1, noden); LOADB(n2, 2, noden); LOADB(n3, 3, noden); }
        float dn = dinv[node];
        f32x4 acc = {0.f, 0.f, 0.f, 0.f};
        acc = __builtin_amdgcn_mfma_f32_16x16x32_bf16(ahi[0], b0, acc, 0, 0, 0);
        acc = __builtin_amdgcn_mfma_f32_16x16x32_bf16(alo[0], b0, acc, 0, 0, 0);
        acc = __builtin_amdgcn_mfma_f32_16x16x32_bf16(ahi[1], b1, acc, 0, 0, 0);
        acc = __builtin_amdgcn_mfma_f32_16x16x32_bf16(alo[1], b1, acc, 0, 0, 0);
        acc = __builtin_amdgcn_mfma_f32_16x16x32_bf16(ahi[2], b2, acc, 0, 0, 0);
        acc = __builtin_amdgcn_mfma_f32_16x16x32_bf16(alo[2], b2, acc, 0, 0, 0);
        acc = __builtin_amdgcn_mfma_f32_16x16x32_bf16(ahi[3], b3, acc, 0, 0, 0);
        acc = __builtin_amdgcn_mfma_f32_16x16x32_bf16(alo[3], b3, acc, 0, 0, 0);
        uint2 ov = make_uint2(pk_bf16x2(acc[0] * dn, acc[1] * dn),
                              pk_bf16x2(acc[2] * dn, acc[3] * dn));
        *(uint2*)&Yb[(size_t)node * 64 + w * 8 + lk * 2] = ov;   // row-major
        if (!hn) break;
        nt = ntn; node = noden; b0 = n0; b1 = n1; b2 = n2; b3 = n3;
    }
}

// ---- aggregation: wave = 1 node, full-row gathers, 16 gathers in flight,
// dense per-node sentinel-padded indices via SCALAR loads; SLICED output ----
__global__ __launch_bounds__(256) void agg_kernel(const unsigned int* __restrict__ hs,
                                                  const int2* __restrict__ ninfo,
                                                  const int* __restrict__ dense,
                                                  const float* __restrict__ dinv,
                                                  const float* __restrict__ bias,
                                                  unsigned int* __restrict__ out) {
    int node = blockIdx.x * 4 + (threadIdx.x >> 6);
    if (node >= N_NODES) return;
    int lane = threadIdx.x & 63;
    int2 gi = ninfo[node];
    int dbase = __builtin_amdgcn_readfirstlane(gi.x);
    int r16d  = __builtin_amdgcn_readfirstlane(gi.y);
    const int* row = dense + dbase;                // wave-uniform -> scalar loads
    const char* hb = (const char*)hs;
    int l4 = lane * 4;
    // hoisted epilogue operands
    float dn = dinv[node];
    unsigned int us = hs[(size_t)node * 64 + lane];    // self term
    float bx = bias[lane * 2], by = bias[lane * 2 + 1];
    float ax = 0.f, ay = 0.f;
    for (int e = 0; e < r16d; e += 16) {
        int o[16];
#pragma unroll
        for (int i = 0; i < 16; ++i) o[i] = row[e + i];
        unsigned int u[16];
#pragma unroll
        for (int i = 0; i < 16; ++i) u[i] = *(const unsigned int*)(hb + (o[i] + l4));
        float axl = 0.f, ayl = 0.f;
#pragma unroll
        for (int i = 0; i < 16; ++i) { axl += bf_lo(u[i]); ayl += bf_hi(u[i]); }
        ax += axl; ay += ayl;
    }
    float sx = ax + bf_lo(us), sy = ay + bf_hi(us);
    float ox = fmaxf(fmaf(sx, dn, bx), 0.f);
    float oy = fmaxf(fmaf(sy, dn, by), 0.f);
    // sliced write: slice = lane>>3, u32-in-slice = lane&7
    out[((size_t)(lane >> 3) * N_NODES + node) * 8 + (lane & 7)] = pk_bf16x2(ox, oy);
}

// ---- pooling + linear head (reads SLICED packed bf16 h) ----
__global__ __launch_bounds__(256) void pool_kernel(const unsigned int* __restrict__ h,
                                                   const int* __restrict__ gptr,
                                                   const float* __restrict__ lin_w,
                                                   const float* __restrict__ lin_b,
                                                   float* __restrict__ out) {
    __shared__ float part[4];
    int g = blockIdx.x;
    int s = gptr[g], epos = gptr[g + 1];
    int w = threadIdx.x >> 6, lane = threadIdx.x & 63;
    size_t sbase = (size_t)(lane >> 3) * N_NODES * 8 + (lane & 7);
    float2 wv = *(const float2*)(lin_w + lane * 2);
    float acc = 0.f;
    for (int n = s + w; n < epos; n += 4) {
        unsigned int u = h[sbase + (size_t)n * 8];
        acc += bf_lo(u) * wv.x + bf_hi(u) * wv.y;
    }
#pragma unroll
    for (int off = 32; off > 0; off >>= 1) acc += __shfl_down(acc, off, 64);
    if (lane == 0) part[w] = acc;
    __syncthreads();
    if (threadIdx.x == 0) {
        float t = (part[0] + part[1]) + (part[2] + part[3]);
        float c = (float)(epos - s);
        if (c < 1.f) c = 1.f;
        out[g] = t / c + lin_b[0];
    }
}

extern "C" void kernel_launch(void* const* d_in, const int* in_sizes, int n_in,
                              void* d_out, int out_size, void* d_ws, size_t ws_size,
                              hipStream_t stream) {
    const float* x       = (const float*)d_in[0];
    const int*   eidx    = (const int*)d_in[1];
    const int*   batch   = (const int*)d_in[2];
    const float* conv_w0 = (const float*)d_in[3];
    const float* conv_b0 = (const float*)d_in[4];
    const float* conv_ws = (const float*)d_in[5];
    const float* conv_bs = (const float*)d_in[6];
    const float* lin_w   = (const float*)d_in[7];
    const float* lin_b   = (const float*)d_in[8];
    const int* srcI = eidx;
    const int* dstI = eidx + N_EDGES;

    char* ws = (char*)d_ws;
    size_t off = 0;
    auto alloc = [&](size_t bytes) {
        void* p = ws + off;
        off += (bytes + 255) & ~(size_t)255;
        return p;
    };
    unsigned int*  xb      = (unsigned int*)alloc((size_t)N_NODES * 64 * 4);       // sliced
    unsigned int*  hsb     = (unsigned int*)alloc((size_t)(N_NODES + 1) * 64 * 4); // row-major + sentinel
    int*           scratch = (int*)alloc((size_t)N_NODES * CAP * 4);
    int*           dense   = (int*)alloc((size_t)(N_EDGES + 16 * N_NODES) * 4);
    int*           part    = (int*)alloc((size_t)NBUCK * BCAP * 4);
    int*           cnt     = (int*)alloc((size_t)N_NODES * 4);
    float*         dinv    = (float*)alloc((size_t)N_NODES * 4);
    int*           bcur    = (int*)alloc((size_t)(NBUCK + 1) * 4);  // +1: dense cursor
    int*           gptr    = (int*)alloc((size_t)(N_GRAPHS + 1) * 4);
    int2*          ninfo   = (int2*)alloc((size_t)N_NODES * 8);
    unsigned short* wthi = (unsigned short*)alloc((size_t)NLAYERS * DH * DH * 2);
    unsigned short* wtlo = (unsigned short*)alloc((size_t)NLAYERS * DH * DH * 2);
    int* gcursor = bcur + NBUCK;
    (void)ws_size; (void)in_sizes; (void)n_in; (void)out_size;

    hipMemsetAsync(bcur, 0, (size_t)(NBUCK + 1) * 4, stream);

    binA_kernel<<<BLOCKS_A, 256, 0, stream>>>(srcI, dstI, bcur, part);
    binB_kernel<<<NBUCK, 256, 0, stream>>>(part, bcur, cnt, scratch, ninfo, gcursor, dense);
    prep_kernel<<<(N_NODES + 255) / 256, 256, 0, stream>>>(cnt, dinv, hsb, batch, gptr);
    wsplit_kernel<<<(NLAYERS * DH * DH + 255) / 256, 256, 0, stream>>>(conv_w0, conv_ws,
                                                                       wthi, wtlo);
    xconv_kernel<<<(N_NODES * 32 + 255) / 256, 256, 0, stream>>>(x, xb);

    for (int l = 0; l < NLAYERS; ++l) {
        const float* b = (l == 0) ? conv_b0 : conv_bs + (size_t)(l - 1) * DH;
        mfma_gemm_kernel<<<2048, 512, 0, stream>>>(xb, wthi + (size_t)l * DH * DH,
                                                   wtlo + (size_t)l * DH * DH, dinv, hsb);
        agg_kernel<<<(N_NODES + 3) / 4, 256, 0, stream>>>(hsb, ninfo, dense, dinv, b, xb);
    }

    pool_kernel<<<N_GRAPHS, 256, 0, stream>>>(xb, gptr, lin_w, lin_b, (float*)d_out);
}

// Round 16
// 578.314 us; speedup vs baseline: 1.0470x; 1.0470x over previous
//
#include <hip/hip_runtime.h>

#define N_NODES 100000
#define N_EDGES 1600000
#define N_GRAPHS 512
#define DH 128
#define CAP 64             // per-node edge capacity in scratch (max in-deg ~42)
#define NLAYERS 6
#define NBUCK 196          // buckets of 512 nodes
#define BCAP 8960          // per-bucket edge capacity (mean 8163, +8 sigma)
#define CHUNK_A 4096
#define BLOCKS_A ((N_EDGES + CHUNK_A - 1) / CHUNK_A)   // 391
#define SENT_OFF (N_NODES << 8)      // sentinel byte-offset -> zero row at N_NODES
#define NT_TILES (N_NODES / 16)      // 6250
#define NPAIRS (NT_TILES / 2)        // 3125

typedef short bf16x8 __attribute__((ext_vector_type(8)));
typedef float f32x4 __attribute__((ext_vector_type(4)));

// ---- bf16 helpers (RNE) ----
__device__ inline unsigned int pk_bf16x2(float a, float b) {
    unsigned int ua = __float_as_uint(a), ub = __float_as_uint(b);
    ua += 0x7fffu + ((ua >> 16) & 1u);
    ub += 0x7fffu + ((ub >> 16) & 1u);
    return (ua >> 16) | (ub & 0xffff0000u);
}
__device__ inline unsigned short bf16_rne(float f) {
    unsigned int u = __float_as_uint(f);
    u += 0x7fffu + ((u >> 16) & 1u);
    return (unsigned short)(u >> 16);
}
__device__ inline float bf_lo(unsigned int u) { return __uint_as_float(u << 16); }
__device__ inline float bf_hi(unsigned int u) { return __uint_as_float(u & 0xffff0000u); }

// ---- Pass A: radix partition edges into NBUCK buckets (by dst>>9), packed ----
// entry = (src << 9) | (dst & 511)
__global__ __launch_bounds__(256) void binA_kernel(const int* __restrict__ src,
                                                   const int* __restrict__ dst,
                                                   int* __restrict__ bcur,
                                                   int* __restrict__ part) {
    __shared__ int hist[NBUCK];
    __shared__ int base[NBUCK];
    int tid = threadIdx.x;
    int e0 = blockIdx.x * CHUNK_A;
    int myE = N_EDGES - e0; if (myE > CHUNK_A) myE = CHUNK_A;
    for (int b = tid; b < NBUCK; b += 256) hist[b] = 0;
    __syncthreads();
    for (int i = tid; i < myE; i += 256) {
        int d = dst[e0 + i];
        atomicAdd(&hist[d >> 9], 1);
    }
    __syncthreads();
    for (int b = tid; b < NBUCK; b += 256) {
        base[b] = atomicAdd(&bcur[b], hist[b]);
        hist[b] = 0;                      // reuse as local cursor
    }
    __syncthreads();
    for (int i = tid; i < myE; i += 256) {
        int s = src[e0 + i], d = dst[e0 + i];
        int b = d >> 9;
        int off = atomicAdd(&hist[b], 1);
        int pos = base[b] + off;
        if (pos < BCAP) part[(size_t)b * BCAP + pos] = (s << 9) | (d & 511);
    }
}

// ---- Pass B: scatter into CAP-padded scratch (entries = src<<8 byte offsets),
// then repack into DENSE per-node stream padded to round8(deg) with sentinels.
// ninfo[n] = {dense base, round8(deg)}.
__global__ __launch_bounds__(256) void binB_kernel(const int* __restrict__ part,
                                                   const int* __restrict__ bcur,
                                                   int* __restrict__ cnt,
                                                   int* __restrict__ scratch,
                                                   int2* __restrict__ ninfo,
                                                   int* __restrict__ gcursor,
                                                   int* __restrict__ dense) {
    __shared__ int lcnt[512];
    __shared__ int nbase[512];
    __shared__ int psum[64];
    __shared__ int bucket_base;
    int tid = threadIdx.x;
    int b = blockIdx.x;
    int node0 = b << 9;
    for (int i = tid; i < 512; i += 256) lcnt[i] = 0;
    __syncthreads();
    int m = bcur[b]; if (m > BCAP) m = BCAP;
    const int* p = part + (size_t)b * BCAP;
    for (int i = tid; i < m; i += 256) {
        int v = p[i];
        int dl = v & 511;
        int sv = (int)(((unsigned int)v) >> 9);
        int r = atomicAdd(&lcnt[dl], 1);
        if (r < CAP) scratch[(size_t)(node0 + dl) * CAP + r] = sv << 8;
    }
    __syncthreads();
    for (int i = tid; i < 512; i += 256) {
        int n = node0 + i;
        if (n < N_NODES) cnt[n] = lcnt[i];
    }
    if (tid < 64) {
        int acc = 0;
        int base = tid * 8;
#pragma unroll
        for (int i = 0; i < 8; ++i) {
            int dg = lcnt[base + i]; if (dg > CAP) dg = CAP;
            acc += (dg + 7) & ~7;
        }
        psum[tid] = acc;
    }
    __syncthreads();
    if (tid == 0) {
        int acc = 0;
        for (int i = 0; i < 64; ++i) { int t = psum[i]; psum[i] = acc; acc += t; }
        bucket_base = atomicAdd(gcursor, acc);
    }
    __syncthreads();
    if (tid < 64) {
        int off = psum[tid];
        int base = tid * 8;
#pragma unroll
        for (int i = 0; i < 8; ++i) {
            int dg = lcnt[base + i]; if (dg > CAP) dg = CAP;
            nbase[base + i] = off;
            off += (dg + 7) & ~7;
        }
    }
    __syncthreads();
    int bb = bucket_base;
    for (int i = tid; i < 512; i += 256) {
        int n = node0 + i;
        if (n < N_NODES) {
            int dg = lcnt[i]; if (dg > CAP) dg = CAP;
            ninfo[n] = make_int2(bb + nbase[i], (dg + 7) & ~7);
        }
    }
    // repack: 32 nodes per round, 8 threads per node
    for (int nb = 0; nb < 512; nb += 32) {
        int nl = nb + (tid >> 3);
        int n = node0 + nl;
        if (n < N_NODES) {
            int dg = lcnt[nl]; if (dg > CAP) dg = CAP;
            int r8 = (dg + 7) & ~7;
            int* dst = dense + bb + nbase[nl];
            for (int e = tid & 7; e < r8; e += 8)
                dst[e] = (e < dg) ? scratch[(size_t)n * CAP + e] : SENT_OFF;
        }
    }
}

// ---- dinv + zero the row-major sentinel row (64 u32) ----
__global__ void dinv_kernel(const int* __restrict__ cnt, float* __restrict__ dinv,
                            unsigned int* __restrict__ hsb) {
    int n = blockIdx.x * 256 + threadIdx.x;
    if (n < N_NODES) dinv[n] = rsqrtf((float)(cnt[n] + 1));
    if (n < 64) hsb[(size_t)N_NODES * 64 + n] = 0u;
}

// ---- W split: WThi/WTlo[l][c][k] = hi/lo bf16 of W_l[k][c] (transposed) ----
__global__ void wsplit_kernel(const float* __restrict__ w0, const float* __restrict__ ws,
                              unsigned short* __restrict__ wthi,
                              unsigned short* __restrict__ wtlo) {
    int i = blockIdx.x * 256 + threadIdx.x;
    if (i >= NLAYERS * DH * DH) return;
    int l = i >> 14;
    int r = i & 16383;
    int c = r >> 7, k = r & 127;
    const float* W = (l == 0) ? w0 : ws + (size_t)(l - 1) * DH * DH;
    float f = W[k * DH + c];
    unsigned short hi = bf16_rne(f);
    float hif = __uint_as_float(((unsigned int)hi) << 16);
    unsigned short lo = bf16_rne(f - hif);
    wthi[i] = hi;
    wtlo[i] = lo;
}

// ---- x fp32 -> packed bf16x2, SLICE-MAJOR xb: xb[(cu>>3)*N + node][cu&7] ----
__global__ void xconv_kernel(const float* __restrict__ x, unsigned int* __restrict__ xb) {
    int i = blockIdx.x * 256 + threadIdx.x;       // one uint2 (4 floats) per thread
    if (i >= N_NODES * 32) return;
    float4 v = *(const float4*)&x[(size_t)i * 4];
    int node = i >> 5;
    int cu = (i & 31) * 2;
    int ss = cu >> 3, o = cu & 7;
    uint2 ov = make_uint2(pk_bf16x2(v.x, v.y), pk_bf16x2(v.z, v.w));
    *(uint2*)&xb[((size_t)ss * N_NODES + node) * 8 + o] = ov;
}

// ---- MFMA GEMM, PAIR-UNROLLED persistent loop with 1-deep prefetch ----
// Each wave handles two 16-node tiles per iteration: 8 independent LOADBs
// in flight. Sliced B-loads (coalesced), ROW-MAJOR stores to hsb.
#define LOADB(v, kb, nd) \
    v = *(const bf16x8*)&Xb[(((size_t)(2*(kb) + (lk >> 1)) * N_NODES + (nd)) * 8) + (lk & 1) * 4];

__global__ __launch_bounds__(512) void mfma_gemm_kernel(const unsigned int* __restrict__ Xb,
                                                        const unsigned short* __restrict__ WThi,
                                                        const unsigned short* __restrict__ WTlo,
                                                        const float* __restrict__ dinv,
                                                        unsigned int* __restrict__ Yb) {
    int w = threadIdx.x >> 6;
    int lane = threadIdx.x & 63;
    int l15 = lane & 15, lk = lane >> 4;          // lk in 0..3
    int wc = w * 16 + l15;                        // A row (output dim)
    bf16x8 ahi[4], alo[4];
#pragma unroll
    for (int kb = 0; kb < 4; ++kb) {
        int k0 = kb * 32 + lk * 8;
        ahi[kb] = *(const bf16x8*)&WThi[wc * DH + k0];
        alo[kb] = *(const bf16x8*)&WTlo[wc * DH + k0];
    }
    int p = blockIdx.x;
    if (p >= NPAIRS) return;
    int nodeA = p * 32 + l15;
    int nodeB = nodeA + 16;
    bf16x8 a0, a1, a2, a3, b0, b1, b2, b3;
    LOADB(a0, 0, nodeA); LOADB(a1, 1, nodeA); LOADB(a2, 2, nodeA); LOADB(a3, 3, nodeA);
    LOADB(b0, 0, nodeB); LOADB(b1, 1, nodeB); LOADB(b2, 2, nodeB); LOADB(b3, 3, nodeB);
    for (;;) {
        int pn = p + gridDim.x;
        bool hn = pn < NPAIRS;
        int nodeAn = pn * 32 + l15;
        int nodeBn = nodeAn + 16;
        bf16x8 na0 = a0, na1 = a1, na2 = a2, na3 = a3;
        bf16x8 nb0 = b0, nb1 = b1, nb2 = b2, nb3 = b3;
        if (hn) {
            LOADB(na0, 0, nodeAn); LOADB(na1, 1, nodeAn); LOADB(na2, 2, nodeAn); LOADB(na3, 3, nodeAn);
            LOADB(nb0, 0, nodeBn); LOADB(nb1, 1, nodeBn); LOADB(nb2, 2, nodeBn); LOADB(nb3, 3, nodeBn);
        }
        float dnA = dinv[nodeA];
        float dnB = dinv[nodeB];
        f32x4 accA = {0.f, 0.f, 0.f, 0.f};
        f32x4 accB = {0.f, 0.f, 0.f, 0.f};
        accA = __builtin_amdgcn_mfma_f32_16x16x32_bf16(ahi[0], a0, accA, 0, 0, 0);
        accB = __builtin_amdgcn_mfma_f32_16x16x32_bf16(ahi[0], b0, accB, 0, 0, 0);
        accA = __builtin_amdgcn_mfma_f32_16x16x32_bf16(alo[0], a0, accA, 0, 0, 0);
        accB = __builtin_amdgcn_mfma_f32_16x16x32_bf16(alo[0], b0, accB, 0, 0, 0);
        accA = __builtin_amdgcn_mfma_f32_16x16x32_bf16(ahi[1], a1, accA, 0, 0, 0);
        accB = __builtin_amdgcn_mfma_f32_16x16x32_bf16(ahi[1], b1, accB, 0, 0, 0);
        accA = __builtin_amdgcn_mfma_f32_16x16x32_bf16(alo[1], a1, accA, 0, 0, 0);
        accB = __builtin_amdgcn_mfma_f32_16x16x32_bf16(alo[1], b1, accB, 0, 0, 0);
        accA = __builtin_amdgcn_mfma_f32_16x16x32_bf16(ahi[2], a2, accA, 0, 0, 0);
        accB = __builtin_amdgcn_mfma_f32_16x16x32_bf16(ahi[2], b2, accB, 0, 0, 0);
        accA = __builtin_amdgcn_mfma_f32_16x16x32_bf16(alo[2], a2, accA, 0, 0, 0);
        accB = __builtin_amdgcn_mfma_f32_16x16x32_bf16(alo[2], b2, accB, 0, 0, 0);
        accA = __builtin_amdgcn_mfma_f32_16x16x32_bf16(ahi[3], a3, accA, 0, 0, 0);
        accB = __builtin_amdgcn_mfma_f32_16x16x32_bf16(ahi[3], b3, accB, 0, 0, 0);
        accA = __builtin_amdgcn_mfma_f32_16x16x32_bf16(alo[3], a3, accA, 0, 0, 0);
        accB = __builtin_amdgcn_mfma_f32_16x16x32_bf16(alo[3], b3, accB, 0, 0, 0);
        uint2 ovA = make_uint2(pk_bf16x2(accA[0] * dnA, accA[1] * dnA),
                               pk_bf16x2(accA[2] * dnA, accA[3] * dnA));
        uint2 ovB = make_uint2(pk_bf16x2(accB[0] * dnB, accB[1] * dnB),
                               pk_bf16x2(accB[2] * dnB, accB[3] * dnB));
        *(uint2*)&Yb[(size_t)nodeA * 64 + w * 8 + lk * 2] = ovA;   // row-major
        *(uint2*)&Yb[(size_t)nodeB * 64 + w * 8 + lk * 2] = ovB;
        if (!hn) break;
        p = pn; nodeA = nodeAn; nodeB = nodeBn;
        a0 = na0; a1 = na1; a2 = na2; a3 = na3;
        b0 = nb0; b1 = nb1; b2 = nb2; b3 = nb3;
    }
}

// ---- aggregation: wave = 1 node, full-row gathers (256B/instr, 2 lines/edge),
// dense per-node sentinel-padded indices via SCALAR loads; SLICED output ----
__global__ __launch_bounds__(256) void agg_kernel(const unsigned int* __restrict__ hs,
                                                  const int2* __restrict__ ninfo,
                                                  const int* __restrict__ dense,
                                                  const float* __restrict__ dinv,
                                                  const float* __restrict__ bias,
                                                  unsigned int* __restrict__ out) {
    int node = blockIdx.x * 4 + (threadIdx.x >> 6);
    if (node >= N_NODES) return;
    int lane = threadIdx.x & 63;
    int2 gi = ninfo[node];
    int dbase = __builtin_amdgcn_readfirstlane(gi.x);
    int r8d   = __builtin_amdgcn_readfirstlane(gi.y);
    const int* row = dense + dbase;                // wave-uniform -> scalar loads
    const char* hb = (const char*)hs;
    int l4 = lane * 4;
    // hoisted epilogue operands
    float dn = dinv[node];
    unsigned int us = hs[(size_t)node * 64 + lane];    // self term
    float bx = bias[lane * 2], by = bias[lane * 2 + 1];
    float ax = 0.f, ay = 0.f;
    for (int e = 0; e < r8d; e += 8) {
        int o0 = row[e + 0], o1 = row[e + 1], o2 = row[e + 2], o3 = row[e + 3];
        int o4 = row[e + 4], o5 = row[e + 5], o6 = row[e + 6], o7 = row[e + 7];
        unsigned int u0 = *(const unsigned int*)(hb + (o0 + l4));
        unsigned int u1 = *(const unsigned int*)(hb + (o1 + l4));
        unsigned int u2 = *(const unsigned int*)(hb + (o2 + l4));
        unsigned int u3 = *(const unsigned int*)(hb + (o3 + l4));
        unsigned int u4 = *(const unsigned int*)(hb + (o4 + l4));
        unsigned int u5 = *(const unsigned int*)(hb + (o5 + l4));
        unsigned int u6 = *(const unsigned int*)(hb + (o6 + l4));
        unsigned int u7 = *(const unsigned int*)(hb + (o7 + l4));
        ax += ((bf_lo(u0) + bf_lo(u1)) + (bf_lo(u2) + bf_lo(u3)))
            + ((bf_lo(u4) + bf_lo(u5)) + (bf_lo(u6) + bf_lo(u7)));
        ay += ((bf_hi(u0) + bf_hi(u1)) + (bf_hi(u2) + bf_hi(u3)))
            + ((bf_hi(u4) + bf_hi(u5)) + (bf_hi(u6) + bf_hi(u7)));
    }
    float sx = ax + bf_lo(us), sy = ay + bf_hi(us);
    float ox = fmaxf(fmaf(sx, dn, bx), 0.f);
    float oy = fmaxf(fmaf(sy, dn, by), 0.f);
    // sliced write: slice = lane>>3, u32-in-slice = lane&7
    out[((size_t)(lane >> 3) * N_NODES + node) * 8 + (lane & 7)] = pk_bf16x2(ox, oy);
}

// ---- graph boundaries from sorted batch ----
__global__ void gptr_kernel(const int* __restrict__ batch, int* __restrict__ gptr) {
    int n = blockIdx.x * 256 + threadIdx.x;
    if (n >= N_NODES) return;
    int b1 = batch[n];
    if (n == 0) {
        for (int g = 0; g <= b1; ++g) gptr[g] = 0;
    } else {
        int b0 = batch[n - 1];
        for (int g = b0 + 1; g <= b1; ++g) gptr[g] = n;
    }
    if (n == N_NODES - 1) {
        for (int g = b1 + 1; g <= N_GRAPHS; ++g) gptr[g] = N_NODES;
    }
}

// ---- pooling + linear head (reads SLICED packed bf16 h) ----
__global__ __launch_bounds__(256) void pool_kernel(const unsigned int* __restrict__ h,
                                                   const int* __restrict__ gptr,
                                                   const float* __restrict__ lin_w,
                                                   const float* __restrict__ lin_b,
                                                   float* __restrict__ out) {
    __shared__ float part[4];
    int g = blockIdx.x;
    int s = gptr[g], epos = gptr[g + 1];
    int w = threadIdx.x >> 6, lane = threadIdx.x & 63;
    size_t sbase = (size_t)(lane >> 3) * N_NODES * 8 + (lane & 7);
    float2 wv = *(const float2*)(lin_w + lane * 2);
    float acc = 0.f;
    for (int n = s + w; n < epos; n += 4) {
        unsigned int u = h[sbase + (size_t)n * 8];
        acc += bf_lo(u) * wv.x + bf_hi(u) * wv.y;
    }
#pragma unroll
    for (int off = 32; off > 0; off >>= 1) acc += __shfl_down(acc, off, 64);
    if (lane == 0) part[w] = acc;
    __syncthreads();
    if (threadIdx.x == 0) {
        float t = (part[0] + part[1]) + (part[2] + part[3]);
        float c = (float)(epos - s);
        if (c < 1.f) c = 1.f;
        out[g] = t / c + lin_b[0];
    }
}

extern "C" void kernel_launch(void* const* d_in, const int* in_sizes, int n_in,
                              void* d_out, int out_size, void* d_ws, size_t ws_size,
                              hipStream_t stream) {
    const float* x       = (const float*)d_in[0];
    const int*   eidx    = (const int*)d_in[1];
    const int*   batch   = (const int*)d_in[2];
    const float* conv_w0 = (const float*)d_in[3];
    const float* conv_b0 = (const float*)d_in[4];
    const float* conv_ws = (const float*)d_in[5];
    const float* conv_bs = (const float*)d_in[6];
    const float* lin_w   = (const float*)d_in[7];
    const float* lin_b   = (const float*)d_in[8];
    const int* srcI = eidx;
    const int* dstI = eidx + N_EDGES;

    char* ws = (char*)d_ws;
    size_t off = 0;
    auto alloc = [&](size_t bytes) {
        void* p = ws + off;
        off += (bytes + 255) & ~(size_t)255;
        return p;
    };
    unsigned int*  xb      = (unsigned int*)alloc((size_t)N_NODES * 64 * 4);       // sliced
    unsigned int*  hsb     = (unsigned int*)alloc((size_t)(N_NODES + 1) * 64 * 4); // row-major + sentinel
    int*           scratch = (int*)alloc((size_t)N_NODES * CAP * 4);
    int*           dense   = (int*)alloc((size_t)(N_EDGES + 8 * N_NODES) * 4);
    int*           part    = (int*)alloc((size_t)NBUCK * BCAP * 4);
    int*           cnt     = (int*)alloc((size_t)N_NODES * 4);
    float*         dinv    = (float*)alloc((size_t)N_NODES * 4);
    int*           bcur    = (int*)alloc((size_t)(NBUCK + 1) * 4);  // +1: dense cursor
    int*           gptr    = (int*)alloc((size_t)(N_GRAPHS + 1) * 4);
    int2*          ninfo   = (int2*)alloc((size_t)N_NODES * 8);
    unsigned short* wthi = (unsigned short*)alloc((size_t)NLAYERS * DH * DH * 2);
    unsigned short* wtlo = (unsigned short*)alloc((size_t)NLAYERS * DH * DH * 2);
    int* gcursor = bcur + NBUCK;
    (void)ws_size; (void)in_sizes; (void)n_in; (void)out_size;

    hipMemsetAsync(bcur, 0, (size_t)(NBUCK + 1) * 4, stream);

    binA_kernel<<<BLOCKS_A, 256, 0, stream>>>(srcI, dstI, bcur, part);
    binB_kernel<<<NBUCK, 256, 0, stream>>>(part, bcur, cnt, scratch, ninfo, gcursor, dense);
    dinv_kernel<<<(N_NODES + 255) / 256, 256, 0, stream>>>(cnt, dinv, hsb);
    gptr_kernel<<<(N_NODES + 255) / 256, 256, 0, stream>>>(batch, gptr);
    wsplit_kernel<<<(NLAYERS * DH * DH + 255) / 256, 256, 0, stream>>>(conv_w0, conv_ws,
                                                                       wthi, wtlo);
    xconv_kernel<<<(N_NODES * 32 + 255) / 256, 256, 0, stream>>>(x, xb);

    for (int l = 0; l < NLAYERS; ++l) {
        const float* b = (l == 0) ? conv_b0 : conv_bs + (size_t)(l - 1) * DH;
        mfma_gemm_kernel<<<1024, 512, 0, stream>>>(xb, wthi + (size_t)l * DH * DH,
                                                   wtlo + (size_t)l * DH * DH, dinv, hsb);
        agg_kernel<<<(N_NODES + 3) / 4, 256, 0, stream>>>(hsb, ninfo, dense, dinv, b, xb);
    }

    pool_kernel<<<N_GRAPHS, 256, 0, stream>>>(xb, gptr, lin_w, lin_b, (float*)d_out);
}

// Round 17
// 560.468 us; speedup vs baseline: 1.0803x; 1.0318x over previous
//
#include <hip/hip_runtime.h>

#define N_NODES 100000
#define N_EDGES 1600000
#define N_GRAPHS 512
#define DH 128
#define CAP 64             // per-node edge capacity (max in-deg ~42 for Poisson(16))
#define NLAYERS 6
#define NBUCK 196          // buckets of 512 nodes
#define BCAP 8960          // per-bucket edge capacity (mean 8163, +8 sigma)
#define CHUNK_A 4096
#define BLOCKS_A ((N_EDGES + CHUNK_A - 1) / CHUNK_A)   // 391
#define SENT_OFF (N_NODES << 8)      // sentinel byte-offset -> zero row at N_NODES
#define NT_TILES (N_NODES / 16)      // 6250
#define NPAIRS (NT_TILES / 2)        // 3125

typedef short bf16x8 __attribute__((ext_vector_type(8)));
typedef float f32x4 __attribute__((ext_vector_type(4)));

// ---- bf16 helpers (RNE) ----
__device__ inline unsigned int pk_bf16x2(float a, float b) {
    unsigned int ua = __float_as_uint(a), ub = __float_as_uint(b);
    ua += 0x7fffu + ((ua >> 16) & 1u);
    ub += 0x7fffu + ((ub >> 16) & 1u);
    return (ua >> 16) | (ub & 0xffff0000u);
}
__device__ inline unsigned short bf16_rne(float f) {
    unsigned int u = __float_as_uint(f);
    u += 0x7fffu + ((u >> 16) & 1u);
    return (unsigned short)(u >> 16);
}
__device__ inline float bf_lo(unsigned int u) { return __uint_as_float(u << 16); }
__device__ inline float bf_hi(unsigned int u) { return __uint_as_float(u & 0xffff0000u); }

// ---- Pass A: radix partition edges into NBUCK buckets (by dst>>9), packed ----
// entry = (src << 9) | (dst & 511)
__global__ __launch_bounds__(256) void binA_kernel(const int* __restrict__ src,
                                                   const int* __restrict__ dst,
                                                   int* __restrict__ bcur,
                                                   int* __restrict__ part) {
    __shared__ int hist[NBUCK];
    __shared__ int base[NBUCK];
    int tid = threadIdx.x;
    int e0 = blockIdx.x * CHUNK_A;
    int myE = N_EDGES - e0; if (myE > CHUNK_A) myE = CHUNK_A;
    for (int b = tid; b < NBUCK; b += 256) hist[b] = 0;
    __syncthreads();
    for (int i = tid; i < myE; i += 256) {
        int d = dst[e0 + i];
        atomicAdd(&hist[d >> 9], 1);
    }
    __syncthreads();
    for (int b = tid; b < NBUCK; b += 256) {
        base[b] = atomicAdd(&bcur[b], hist[b]);
        hist[b] = 0;                      // reuse as local cursor
    }
    __syncthreads();
    for (int i = tid; i < myE; i += 256) {
        int s = src[e0 + i], d = dst[e0 + i];
        int b = d >> 9;
        int off = atomicAdd(&hist[b], 1);
        int pos = base[b] + off;
        if (pos < BCAP) part[(size_t)b * BCAP + pos] = (s << 9) | (d & 511);
    }
}

// ---- Pass B: count part, compute per-node dense bases, then scatter part
// DIRECTLY into dense (no scratch round-trip); predicated sentinel fill.
// ninfo[n] = {dense base, round8(deg)}.
__global__ __launch_bounds__(256) void binB_kernel(const int* __restrict__ part,
                                                   const int* __restrict__ bcur,
                                                   int* __restrict__ cnt,
                                                   int2* __restrict__ ninfo,
                                                   int* __restrict__ gcursor,
                                                   int* __restrict__ dense) {
    __shared__ int lcnt[512];
    __shared__ int lcur[512];
    __shared__ int nbase[512];
    __shared__ int psum[64];
    __shared__ int bucket_base;
    int tid = threadIdx.x;
    int b = blockIdx.x;
    int node0 = b << 9;
    for (int i = tid; i < 512; i += 256) { lcnt[i] = 0; lcur[i] = 0; }
    __syncthreads();
    int m = bcur[b]; if (m > BCAP) m = BCAP;
    const int* p = part + (size_t)b * BCAP;
    // phase 1: per-node counts
    for (int i = tid; i < m; i += 256) {
        atomicAdd(&lcnt[p[i] & 511], 1);
    }
    __syncthreads();
    for (int i = tid; i < 512; i += 256) {
        int n = node0 + i;
        if (n < N_NODES) cnt[n] = lcnt[i];
    }
    if (tid < 64) {
        int acc = 0;
        int base = tid * 8;
#pragma unroll
        for (int i = 0; i < 8; ++i) {
            int dg = lcnt[base + i]; if (dg > CAP) dg = CAP;
            acc += (dg + 7) & ~7;
        }
        psum[tid] = acc;
    }
    __syncthreads();
    if (tid == 0) {
        int acc = 0;
        for (int i = 0; i < 64; ++i) { int t = psum[i]; psum[i] = acc; acc += t; }
        bucket_base = atomicAdd(gcursor, acc);
    }
    __syncthreads();
    if (tid < 64) {
        int off = psum[tid] + bucket_base;
        int base = tid * 8;
#pragma unroll
        for (int i = 0; i < 8; ++i) {
            int dg = lcnt[base + i]; if (dg > CAP) dg = CAP;
            nbase[base + i] = off;
            off += (dg + 7) & ~7;
        }
    }
    __syncthreads();
    for (int i = tid; i < 512; i += 256) {
        int n = node0 + i;
        if (n < N_NODES) {
            int dg = lcnt[i]; if (dg > CAP) dg = CAP;
            ninfo[n] = make_int2(nbase[i], (dg + 7) & ~7);
        }
    }
    // phase 2: scatter directly into dense
    for (int i = tid; i < m; i += 256) {
        int v = p[i];
        int dl = v & 511;
        int sv = (int)(((unsigned int)v) >> 9);
        int r = atomicAdd(&lcur[dl], 1);
        if (r < CAP) dense[nbase[dl] + r] = sv << 8;
    }
    __syncthreads();
    // sentinel fill: r8-dg < 8 always -> one predicated write per (node, slot)
    for (int nb = 0; nb < 512; nb += 32) {   // 32 nodes per round, 8 thr/node
        int nl = nb + (tid >> 3);
        int n = node0 + nl;
        if (n < N_NODES) {
            int dg = lcnt[nl]; if (dg > CAP) dg = CAP;
            int r8 = (dg + 7) & ~7;
            int e = dg + (tid & 7);
            if (e < r8) dense[nbase[nl] + e] = SENT_OFF;
        }
    }
}

// ---- dinv + zero the row-major sentinel row (64 u32) ----
__global__ void dinv_kernel(const int* __restrict__ cnt, float* __restrict__ dinv,
                            unsigned int* __restrict__ hsb) {
    int n = blockIdx.x * 256 + threadIdx.x;
    if (n < N_NODES) dinv[n] = rsqrtf((float)(cnt[n] + 1));
    if (n < 64) hsb[(size_t)N_NODES * 64 + n] = 0u;
}

// ---- W split: WThi/WTlo[l][c][k] = hi/lo bf16 of W_l[k][c] (transposed) ----
__global__ void wsplit_kernel(const float* __restrict__ w0, const float* __restrict__ ws,
                              unsigned short* __restrict__ wthi,
                              unsigned short* __restrict__ wtlo) {
    int i = blockIdx.x * 256 + threadIdx.x;
    if (i >= NLAYERS * DH * DH) return;
    int l = i >> 14;
    int r = i & 16383;
    int c = r >> 7, k = r & 127;
    const float* W = (l == 0) ? w0 : ws + (size_t)(l - 1) * DH * DH;
    float f = W[k * DH + c];
    unsigned short hi = bf16_rne(f);
    float hif = __uint_as_float(((unsigned int)hi) << 16);
    unsigned short lo = bf16_rne(f - hif);
    wthi[i] = hi;
    wtlo[i] = lo;
}

// ---- x fp32 -> packed bf16x2, SLICE-MAJOR xb: xb[(cu>>3)*N + node][cu&7] ----
__global__ void xconv_kernel(const float* __restrict__ x, unsigned int* __restrict__ xb) {
    int i = blockIdx.x * 256 + threadIdx.x;       // one uint2 (4 floats) per thread
    if (i >= N_NODES * 32) return;
    float4 v = *(const float4*)&x[(size_t)i * 4];
    int node = i >> 5;
    int cu = (i & 31) * 2;
    int ss = cu >> 3, o = cu & 7;
    uint2 ov = make_uint2(pk_bf16x2(v.x, v.y), pk_bf16x2(v.z, v.w));
    *(uint2*)&xb[((size_t)ss * N_NODES + node) * 8 + o] = ov;
}

// ---- MFMA GEMM, PAIR-UNROLLED persistent loop with 1-deep prefetch ----
// Each wave handles two 16-node tiles per iteration: 8 independent LOADBs
// in flight. Sliced B-loads (coalesced), ROW-MAJOR stores to hsb.
// grid = 512: exactly co-resident (2 blocks/CU), ~6 iterations/wave.
#define LOADB(v, kb, nd) \
    v = *(const bf16x8*)&Xb[(((size_t)(2*(kb) + (lk >> 1)) * N_NODES + (nd)) * 8) + (lk & 1) * 4];

__global__ __launch_bounds__(512) void mfma_gemm_kernel(const unsigned int* __restrict__ Xb,
                                                        const unsigned short* __restrict__ WThi,
                                                        const unsigned short* __restrict__ WTlo,
                                                        const float* __restrict__ dinv,
                                                        unsigned int* __restrict__ Yb) {
    int w = threadIdx.x >> 6;
    int lane = threadIdx.x & 63;
    int l15 = lane & 15, lk = lane >> 4;          // lk in 0..3
    int wc = w * 16 + l15;                        // A row (output dim)
    bf16x8 ahi[4], alo[4];
#pragma unroll
    for (int kb = 0; kb < 4; ++kb) {
        int k0 = kb * 32 + lk * 8;
        ahi[kb] = *(const bf16x8*)&WThi[wc * DH + k0];
        alo[kb] = *(const bf16x8*)&WTlo[wc * DH + k0];
    }
    int p = blockIdx.x;
    if (p >= NPAIRS) return;
    int nodeA = p * 32 + l15;
    int nodeB = nodeA + 16;
    bf16x8 a0, a1, a2, a3, b0, b1, b2, b3;
    LOADB(a0, 0, nodeA); LOADB(a1, 1, nodeA); LOADB(a2, 2, nodeA); LOADB(a3, 3, nodeA);
    LOADB(b0, 0, nodeB); LOADB(b1, 1, nodeB); LOADB(b2, 2, nodeB); LOADB(b3, 3, nodeB);
    for (;;) {
        int pn = p + gridDim.x;
        bool hn = pn < NPAIRS;
        int nodeAn = pn * 32 + l15;
        int nodeBn = nodeAn + 16;
        bf16x8 na0 = a0, na1 = a1, na2 = a2, na3 = a3;
        bf16x8 nb0 = b0, nb1 = b1, nb2 = b2, nb3 = b3;
        if (hn) {
            LOADB(na0, 0, nodeAn); LOADB(na1, 1, nodeAn); LOADB(na2, 2, nodeAn); LOADB(na3, 3, nodeAn);
            LOADB(nb0, 0, nodeBn); LOADB(nb1, 1, nodeBn); LOADB(nb2, 2, nodeBn); LOADB(nb3, 3, nodeBn);
        }
        float dnA = dinv[nodeA];
        float dnB = dinv[nodeB];
        f32x4 accA = {0.f, 0.f, 0.f, 0.f};
        f32x4 accB = {0.f, 0.f, 0.f, 0.f};
        accA = __builtin_amdgcn_mfma_f32_16x16x32_bf16(ahi[0], a0, accA, 0, 0, 0);
        accB = __builtin_amdgcn_mfma_f32_16x16x32_bf16(ahi[0], b0, accB, 0, 0, 0);
        accA = __builtin_amdgcn_mfma_f32_16x16x32_bf16(alo[0], a0, accA, 0, 0, 0);
        accB = __builtin_amdgcn_mfma_f32_16x16x32_bf16(alo[0], b0, accB, 0, 0, 0);
        accA = __builtin_amdgcn_mfma_f32_16x16x32_bf16(ahi[1], a1, accA, 0, 0, 0);
        accB = __builtin_amdgcn_mfma_f32_16x16x32_bf16(ahi[1], b1, accB, 0, 0, 0);
        accA = __builtin_amdgcn_mfma_f32_16x16x32_bf16(alo[1], a1, accA, 0, 0, 0);
        accB = __builtin_amdgcn_mfma_f32_16x16x32_bf16(alo[1], b1, accB, 0, 0, 0);
        accA = __builtin_amdgcn_mfma_f32_16x16x32_bf16(ahi[2], a2, accA, 0, 0, 0);
        accB = __builtin_amdgcn_mfma_f32_16x16x32_bf16(ahi[2], b2, accB, 0, 0, 0);
        accA = __builtin_amdgcn_mfma_f32_16x16x32_bf16(alo[2], a2, accA, 0, 0, 0);
        accB = __builtin_amdgcn_mfma_f32_16x16x32_bf16(alo[2], b2, accB, 0, 0, 0);
        accA = __builtin_amdgcn_mfma_f32_16x16x32_bf16(ahi[3], a3, accA, 0, 0, 0);
        accB = __builtin_amdgcn_mfma_f32_16x16x32_bf16(ahi[3], b3, accB, 0, 0, 0);
        accA = __builtin_amdgcn_mfma_f32_16x16x32_bf16(alo[3], a3, accA, 0, 0, 0);
        accB = __builtin_amdgcn_mfma_f32_16x16x32_bf16(alo[3], b3, accB, 0, 0, 0);
        uint2 ovA = make_uint2(pk_bf16x2(accA[0] * dnA, accA[1] * dnA),
                               pk_bf16x2(accA[2] * dnA, accA[3] * dnA));
        uint2 ovB = make_uint2(pk_bf16x2(accB[0] * dnB, accB[1] * dnB),
                               pk_bf16x2(accB[2] * dnB, accB[3] * dnB));
        *(uint2*)&Yb[(size_t)nodeA * 64 + w * 8 + lk * 2] = ovA;   // row-major
        *(uint2*)&Yb[(size_t)nodeB * 64 + w * 8 + lk * 2] = ovB;
        if (!hn) break;
        p = pn; nodeA = nodeAn; nodeB = nodeBn;
        a0 = na0; a1 = na1; a2 = na2; a3 = na3;
        b0 = nb0; b1 = nb1; b2 = nb2; b3 = nb3;
    }
}

// ---- aggregation: wave = 1 node, full-row gathers (256B/instr, 2 lines/edge),
// dense per-node sentinel-padded indices via SCALAR loads; SLICED output ----
__global__ __launch_bounds__(256) void agg_kernel(const unsigned int* __restrict__ hs,
                                                  const int2* __restrict__ ninfo,
                                                  const int* __restrict__ dense,
                                                  const float* __restrict__ dinv,
                                                  const float* __restrict__ bias,
                                                  unsigned int* __restrict__ out) {
    int node = blockIdx.x * 4 + (threadIdx.x >> 6);
    if (node >= N_NODES) return;
    int lane = threadIdx.x & 63;
    int2 gi = ninfo[node];
    int dbase = __builtin_amdgcn_readfirstlane(gi.x);
    int r8d   = __builtin_amdgcn_readfirstlane(gi.y);
    const int* row = dense + dbase;                // wave-uniform -> scalar loads
    const char* hb = (const char*)hs;
    int l4 = lane * 4;
    // hoisted epilogue operands
    float dn = dinv[node];
    unsigned int us = hs[(size_t)node * 64 + lane];    // self term
    float bx = bias[lane * 2], by = bias[lane * 2 + 1];
    float ax = 0.f, ay = 0.f;
    for (int e = 0; e < r8d; e += 8) {
        int o0 = row[e + 0], o1 = row[e + 1], o2 = row[e + 2], o3 = row[e + 3];
        int o4 = row[e + 4], o5 = row[e + 5], o6 = row[e + 6], o7 = row[e + 7];
        unsigned int u0 = *(const unsigned int*)(hb + (o0 + l4));
        unsigned int u1 = *(const unsigned int*)(hb + (o1 + l4));
        unsigned int u2 = *(const unsigned int*)(hb + (o2 + l4));
        unsigned int u3 = *(const unsigned int*)(hb + (o3 + l4));
        unsigned int u4 = *(const unsigned int*)(hb + (o4 + l4));
        unsigned int u5 = *(const unsigned int*)(hb + (o5 + l4));
        unsigned int u6 = *(const unsigned int*)(hb + (o6 + l4));
        unsigned int u7 = *(const unsigned int*)(hb + (o7 + l4));
        ax += ((bf_lo(u0) + bf_lo(u1)) + (bf_lo(u2) + bf_lo(u3)))
            + ((bf_lo(u4) + bf_lo(u5)) + (bf_lo(u6) + bf_lo(u7)));
        ay += ((bf_hi(u0) + bf_hi(u1)) + (bf_hi(u2) + bf_hi(u3)))
            + ((bf_hi(u4) + bf_hi(u5)) + (bf_hi(u6) + bf_hi(u7)));
    }
    float sx = ax + bf_lo(us), sy = ay + bf_hi(us);
    float ox = fmaxf(fmaf(sx, dn, bx), 0.f);
    float oy = fmaxf(fmaf(sy, dn, by), 0.f);
    // sliced write: slice = lane>>3, u32-in-slice = lane&7
    out[((size_t)(lane >> 3) * N_NODES + node) * 8 + (lane & 7)] = pk_bf16x2(ox, oy);
}

// ---- graph boundaries from sorted batch ----
__global__ void gptr_kernel(const int* __restrict__ batch, int* __restrict__ gptr) {
    int n = blockIdx.x * 256 + threadIdx.x;
    if (n >= N_NODES) return;
    int b1 = batch[n];
    if (n == 0) {
        for (int g = 0; g <= b1; ++g) gptr[g] = 0;
    } else {
        int b0 = batch[n - 1];
        for (int g = b0 + 1; g <= b1; ++g) gptr[g] = n;
    }
    if (n == N_NODES - 1) {
        for (int g = b1 + 1; g <= N_GRAPHS; ++g) gptr[g] = N_NODES;
    }
}

// ---- pooling + linear head (reads SLICED packed bf16 h) ----
__global__ __launch_bounds__(256) void pool_kernel(const unsigned int* __restrict__ h,
                                                   const int* __restrict__ gptr,
                                                   const float* __restrict__ lin_w,
                                                   const float* __restrict__ lin_b,
                                                   float* __restrict__ out) {
    __shared__ float part[4];
    int g = blockIdx.x;
    int s = gptr[g], epos = gptr[g + 1];
    int w = threadIdx.x >> 6, lane = threadIdx.x & 63;
    size_t sbase = (size_t)(lane >> 3) * N_NODES * 8 + (lane & 7);
    float2 wv = *(const float2*)(lin_w + lane * 2);
    float acc = 0.f;
    for (int n = s + w; n < epos; n += 4) {
        unsigned int u = h[sbase + (size_t)n * 8];
        acc += bf_lo(u) * wv.x + bf_hi(u) * wv.y;
    }
#pragma unroll
    for (int off = 32; off > 0; off >>= 1) acc += __shfl_down(acc, off, 64);
    if (lane == 0) part[w] = acc;
    __syncthreads();
    if (threadIdx.x == 0) {
        float t = (part[0] + part[1]) + (part[2] + part[3]);
        float c = (float)(epos - s);
        if (c < 1.f) c = 1.f;
        out[g] = t / c + lin_b[0];
    }
}

extern "C" void kernel_launch(void* const* d_in, const int* in_sizes, int n_in,
                              void* d_out, int out_size, void* d_ws, size_t ws_size,
                              hipStream_t stream) {
    const float* x       = (const float*)d_in[0];
    const int*   eidx    = (const int*)d_in[1];
    const int*   batch   = (const int*)d_in[2];
    const float* conv_w0 = (const float*)d_in[3];
    const float* conv_b0 = (const float*)d_in[4];
    const float* conv_ws = (const float*)d_in[5];
    const float* conv_bs = (const float*)d_in[6];
    const float* lin_w   = (const float*)d_in[7];
    const float* lin_b   = (const float*)d_in[8];
    const int* srcI = eidx;
    const int* dstI = eidx + N_EDGES;

    char* ws = (char*)d_ws;
    size_t off = 0;
    auto alloc = [&](size_t bytes) {
        void* p = ws + off;
        off += (bytes + 255) & ~(size_t)255;
        return p;
    };
    unsigned int*  xb      = (unsigned int*)alloc((size_t)N_NODES * 64 * 4);       // sliced
    unsigned int*  hsb     = (unsigned int*)alloc((size_t)(N_NODES + 1) * 64 * 4); // row-major + sentinel
    int*           dense   = (int*)alloc((size_t)(N_EDGES + 8 * N_NODES) * 4);
    int*           part    = (int*)alloc((size_t)NBUCK * BCAP * 4);
    int*           cnt     = (int*)alloc((size_t)N_NODES * 4);
    float*         dinv    = (float*)alloc((size_t)N_NODES * 4);
    int*           bcur    = (int*)alloc((size_t)(NBUCK + 1) * 4);  // +1: dense cursor
    int*           gptr    = (int*)alloc((size_t)(N_GRAPHS + 1) * 4);
    int2*          ninfo   = (int2*)alloc((size_t)N_NODES * 8);
    unsigned short* wthi = (unsigned short*)alloc((size_t)NLAYERS * DH * DH * 2);
    unsigned short* wtlo = (unsigned short*)alloc((size_t)NLAYERS * DH * DH * 2);
    int* gcursor = bcur + NBUCK;
    (void)ws_size; (void)in_sizes; (void)n_in; (void)out_size;

    hipMemsetAsync(bcur, 0, (size_t)(NBUCK + 1) * 4, stream);

    binA_kernel<<<BLOCKS_A, 256, 0, stream>>>(srcI, dstI, bcur, part);
    binB_kernel<<<NBUCK, 256, 0, stream>>>(part, bcur, cnt, ninfo, gcursor, dense);
    dinv_kernel<<<(N_NODES + 255) / 256, 256, 0, stream>>>(cnt, dinv, hsb);
    gptr_kernel<<<(N_NODES + 255) / 256, 256, 0, stream>>>(batch, gptr);
    wsplit_kernel<<<(NLAYERS * DH * DH + 255) / 256, 256, 0, stream>>>(conv_w0, conv_ws,
                                                                       wthi, wtlo);
    xconv_kernel<<<(N_NODES * 32 + 255) / 256, 256, 0, stream>>>(x, xb);

    for (int l = 0; l < NLAYERS; ++l) {
        const float* b = (l == 0) ? conv_b0 : conv_bs + (size_t)(l - 1) * DH;
        mfma_gemm_kernel<<<512, 512, 0, stream>>>(xb, wthi + (size_t)l * DH * DH,
                                                  wtlo + (size_t)l * DH * DH, dinv, hsb);
        agg_kernel<<<(N_NODES + 3) / 4, 256, 0, stream>>>(hsb, ninfo, dense, dinv, b, xb);
    }

    pool_kernel<<<N_GRAPHS, 256, 0, stream>>>(xb, gptr, lin_w, lin_b, (float*)d_out);
}

// Round 18
// 549.581 us; speedup vs baseline: 1.1017x; 1.0198x over previous
//
#include <hip/hip_runtime.h>

#define N_NODES 100000
#define N_EDGES 1600000
#define N_GRAPHS 512
#define DH 128
#define CAP 64             // per-node edge capacity (max in-deg ~42 for Poisson(16))
#define NLAYERS 6
#define NBUCK 196          // buckets of 512 nodes
#define BCAP 8960          // per-bucket edge capacity (mean 8163, +8 sigma)
#define CHUNK_A 4096
#define BLOCKS_A ((N_EDGES + CHUNK_A - 1) / CHUNK_A)   // 391
#define SENT_OFF (N_NODES << 8)      // sentinel byte-offset -> zero row at N_NODES
#define NT_TILES (N_NODES / 16)      // 6250
#define NPAIRS (NT_TILES / 2)        // 3125

typedef short bf16x8 __attribute__((ext_vector_type(8)));
typedef float f32x4 __attribute__((ext_vector_type(4)));

// ---- bf16 helpers (RNE) ----
__device__ inline unsigned int pk_bf16x2(float a, float b) {
    unsigned int ua = __float_as_uint(a), ub = __float_as_uint(b);
    ua += 0x7fffu + ((ua >> 16) & 1u);
    ub += 0x7fffu + ((ub >> 16) & 1u);
    return (ua >> 16) | (ub & 0xffff0000u);
}
__device__ inline unsigned short bf16_rne(float f) {
    unsigned int u = __float_as_uint(f);
    u += 0x7fffu + ((u >> 16) & 1u);
    return (unsigned short)(u >> 16);
}
__device__ inline float bf_lo(unsigned int u) { return __uint_as_float(u << 16); }
__device__ inline float bf_hi(unsigned int u) { return __uint_as_float(u & 0xffff0000u); }

// ---- Pass A: radix partition edges into NBUCK buckets (by dst>>9), packed ----
// entry = (src << 9) | (dst & 511)
__global__ __launch_bounds__(256) void binA_kernel(const int* __restrict__ src,
                                                   const int* __restrict__ dst,
                                                   int* __restrict__ bcur,
                                                   int* __restrict__ part) {
    __shared__ int hist[NBUCK];
    __shared__ int base[NBUCK];
    int tid = threadIdx.x;
    int e0 = blockIdx.x * CHUNK_A;
    int myE = N_EDGES - e0; if (myE > CHUNK_A) myE = CHUNK_A;
    for (int b = tid; b < NBUCK; b += 256) hist[b] = 0;
    __syncthreads();
    for (int i = tid; i < myE; i += 256) {
        int d = dst[e0 + i];
        atomicAdd(&hist[d >> 9], 1);
    }
    __syncthreads();
    for (int b = tid; b < NBUCK; b += 256) {
        base[b] = atomicAdd(&bcur[b], hist[b]);
        hist[b] = 0;                      // reuse as local cursor
    }
    __syncthreads();
    for (int i = tid; i < myE; i += 256) {
        int s = src[e0 + i], d = dst[e0 + i];
        int b = d >> 9;
        int off = atomicAdd(&hist[b], 1);
        int pos = base[b] + off;
        if (pos < BCAP) part[(size_t)b * BCAP + pos] = (s << 9) | (d & 511);
    }
}

// ---- Pass B: count part, compute per-node dense bases, then scatter part
// DIRECTLY into dense (no scratch round-trip); predicated sentinel fill.
// ninfo[n] = {dense base, round8(deg)}.
__global__ __launch_bounds__(256) void binB_kernel(const int* __restrict__ part,
                                                   const int* __restrict__ bcur,
                                                   int* __restrict__ cnt,
                                                   int2* __restrict__ ninfo,
                                                   int* __restrict__ gcursor,
                                                   int* __restrict__ dense) {
    __shared__ int lcnt[512];
    __shared__ int lcur[512];
    __shared__ int nbase[512];
    __shared__ int psum[64];
    __shared__ int bucket_base;
    int tid = threadIdx.x;
    int b = blockIdx.x;
    int node0 = b << 9;
    for (int i = tid; i < 512; i += 256) { lcnt[i] = 0; lcur[i] = 0; }
    __syncthreads();
    int m = bcur[b]; if (m > BCAP) m = BCAP;
    const int* p = part + (size_t)b * BCAP;
    // phase 1: per-node counts
    for (int i = tid; i < m; i += 256) {
        atomicAdd(&lcnt[p[i] & 511], 1);
    }
    __syncthreads();
    for (int i = tid; i < 512; i += 256) {
        int n = node0 + i;
        if (n < N_NODES) cnt[n] = lcnt[i];
    }
    if (tid < 64) {
        int acc = 0;
        int base = tid * 8;
#pragma unroll
        for (int i = 0; i < 8; ++i) {
            int dg = lcnt[base + i]; if (dg > CAP) dg = CAP;
            acc += (dg + 7) & ~7;
        }
        psum[tid] = acc;
    }
    __syncthreads();
    if (tid == 0) {
        int acc = 0;
        for (int i = 0; i < 64; ++i) { int t = psum[i]; psum[i] = acc; acc += t; }
        bucket_base = atomicAdd(gcursor, acc);
    }
    __syncthreads();
    if (tid < 64) {
        int off = psum[tid] + bucket_base;
        int base = tid * 8;
#pragma unroll
        for (int i = 0; i < 8; ++i) {
            int dg = lcnt[base + i]; if (dg > CAP) dg = CAP;
            nbase[base + i] = off;
            off += (dg + 7) & ~7;
        }
    }
    __syncthreads();
    for (int i = tid; i < 512; i += 256) {
        int n = node0 + i;
        if (n < N_NODES) {
            int dg = lcnt[i]; if (dg > CAP) dg = CAP;
            ninfo[n] = make_int2(nbase[i], (dg + 7) & ~7);
        }
    }
    // phase 2: scatter directly into dense
    for (int i = tid; i < m; i += 256) {
        int v = p[i];
        int dl = v & 511;
        int sv = (int)(((unsigned int)v) >> 9);
        int r = atomicAdd(&lcur[dl], 1);
        if (r < CAP) dense[nbase[dl] + r] = sv << 8;
    }
    __syncthreads();
    // sentinel fill: r8-dg < 8 always -> one predicated write per (node, slot)
    for (int nb = 0; nb < 512; nb += 32) {   // 32 nodes per round, 8 thr/node
        int nl = nb + (tid >> 3);
        int n = node0 + nl;
        if (n < N_NODES) {
            int dg = lcnt[nl]; if (dg > CAP) dg = CAP;
            int r8 = (dg + 7) & ~7;
            int e = dg + (tid & 7);
            if (e < r8) dense[nbase[nl] + e] = SENT_OFF;
        }
    }
}

// ---- dinv + zero the row-major sentinel row (64 u32) ----
__global__ void dinv_kernel(const int* __restrict__ cnt, float* __restrict__ dinv,
                            unsigned int* __restrict__ hsb) {
    int n = blockIdx.x * 256 + threadIdx.x;
    if (n < N_NODES) dinv[n] = rsqrtf((float)(cnt[n] + 1));
    if (n < 64) hsb[(size_t)N_NODES * 64 + n] = 0u;
}

// ---- W convert: WT[l][c][k] = bf16(W_l[k][c]) (transposed, plain RNE) ----
__global__ void wconv_kernel(const float* __restrict__ w0, const float* __restrict__ ws,
                             unsigned short* __restrict__ wt) {
    int i = blockIdx.x * 256 + threadIdx.x;
    if (i >= NLAYERS * DH * DH) return;
    int l = i >> 14;
    int r = i & 16383;
    int c = r >> 7, k = r & 127;
    const float* W = (l == 0) ? w0 : ws + (size_t)(l - 1) * DH * DH;
    wt[i] = bf16_rne(W[k * DH + c]);
}

// ---- x fp32 -> packed bf16x2, SLICE-MAJOR xb: xb[(cu>>3)*N + node][cu&7] ----
__global__ void xconv_kernel(const float* __restrict__ x, unsigned int* __restrict__ xb) {
    int i = blockIdx.x * 256 + threadIdx.x;       // one uint2 (4 floats) per thread
    if (i >= N_NODES * 32) return;
    float4 v = *(const float4*)&x[(size_t)i * 4];
    int node = i >> 5;
    int cu = (i & 31) * 2;
    int ss = cu >> 3, o = cu & 7;
    uint2 ov = make_uint2(pk_bf16x2(v.x, v.y), pk_bf16x2(v.z, v.w));
    *(uint2*)&xb[((size_t)ss * N_NODES + node) * 8 + o] = ov;
}

// ---- MFMA GEMM, PAIR-UNROLLED persistent loop with 1-deep prefetch ----
// Single bf16 W (no hi/lo split): 8 MFMAs per pair-iteration.
// Sliced B-loads (coalesced), ROW-MAJOR stores to hsb. grid = 512.
#define LOADB(v, kb, nd) \
    v = *(const bf16x8*)&Xb[(((size_t)(2*(kb) + (lk >> 1)) * N_NODES + (nd)) * 8) + (lk & 1) * 4];

__global__ __launch_bounds__(512) void mfma_gemm_kernel(const unsigned int* __restrict__ Xb,
                                                        const unsigned short* __restrict__ WT,
                                                        const float* __restrict__ dinv,
                                                        unsigned int* __restrict__ Yb) {
    int w = threadIdx.x >> 6;
    int lane = threadIdx.x & 63;
    int l15 = lane & 15, lk = lane >> 4;          // lk in 0..3
    int wc = w * 16 + l15;                        // A row (output dim)
    bf16x8 aw[4];
#pragma unroll
    for (int kb = 0; kb < 4; ++kb) {
        int k0 = kb * 32 + lk * 8;
        aw[kb] = *(const bf16x8*)&WT[wc * DH + k0];
    }
    int p = blockIdx.x;
    if (p >= NPAIRS) return;
    int nodeA = p * 32 + l15;
    int nodeB = nodeA + 16;
    bf16x8 a0, a1, a2, a3, b0, b1, b2, b3;
    LOADB(a0, 0, nodeA); LOADB(a1, 1, nodeA); LOADB(a2, 2, nodeA); LOADB(a3, 3, nodeA);
    LOADB(b0, 0, nodeB); LOADB(b1, 1, nodeB); LOADB(b2, 2, nodeB); LOADB(b3, 3, nodeB);
    for (;;) {
        int pn = p + gridDim.x;
        bool hn = pn < NPAIRS;
        int nodeAn = pn * 32 + l15;
        int nodeBn = nodeAn + 16;
        bf16x8 na0 = a0, na1 = a1, na2 = a2, na3 = a3;
        bf16x8 nb0 = b0, nb1 = b1, nb2 = b2, nb3 = b3;
        if (hn) {
            LOADB(na0, 0, nodeAn); LOADB(na1, 1, nodeAn); LOADB(na2, 2, nodeAn); LOADB(na3, 3, nodeAn);
            LOADB(nb0, 0, nodeBn); LOADB(nb1, 1, nodeBn); LOADB(nb2, 2, nodeBn); LOADB(nb3, 3, nodeBn);
        }
        float dnA = dinv[nodeA];
        float dnB = dinv[nodeB];
        f32x4 accA = {0.f, 0.f, 0.f, 0.f};
        f32x4 accB = {0.f, 0.f, 0.f, 0.f};
        accA = __builtin_amdgcn_mfma_f32_16x16x32_bf16(aw[0], a0, accA, 0, 0, 0);
        accB = __builtin_amdgcn_mfma_f32_16x16x32_bf16(aw[0], b0, accB, 0, 0, 0);
        accA = __builtin_amdgcn_mfma_f32_16x16x32_bf16(aw[1], a1, accA, 0, 0, 0);
        accB = __builtin_amdgcn_mfma_f32_16x16x32_bf16(aw[1], b1, accB, 0, 0, 0);
        accA = __builtin_amdgcn_mfma_f32_16x16x32_bf16(aw[2], a2, accA, 0, 0, 0);
        accB = __builtin_amdgcn_mfma_f32_16x16x32_bf16(aw[2], b2, accB, 0, 0, 0);
        accA = __builtin_amdgcn_mfma_f32_16x16x32_bf16(aw[3], a3, accA, 0, 0, 0);
        accB = __builtin_amdgcn_mfma_f32_16x16x32_bf16(aw[3], b3, accB, 0, 0, 0);
        uint2 ovA = make_uint2(pk_bf16x2(accA[0] * dnA, accA[1] * dnA),
                               pk_bf16x2(accA[2] * dnA, accA[3] * dnA));
        uint2 ovB = make_uint2(pk_bf16x2(accB[0] * dnB, accB[1] * dnB),
                               pk_bf16x2(accB[2] * dnB, accB[3] * dnB));
        *(uint2*)&Yb[(size_t)nodeA * 64 + w * 8 + lk * 2] = ovA;   // row-major
        *(uint2*)&Yb[(size_t)nodeB * 64 + w * 8 + lk * 2] = ovB;
        if (!hn) break;
        p = pn; nodeA = nodeAn; nodeB = nodeBn;
        a0 = na0; a1 = na1; a2 = na2; a3 = na3;
        b0 = nb0; b1 = nb1; b2 = nb2; b3 = nb3;
    }
}

// ---- aggregation: wave = 1 node, full-row gathers (256B/instr, 2 lines/edge),
// dense per-node sentinel-padded indices via SCALAR loads; SLICED output ----
__global__ __launch_bounds__(256) void agg_kernel(const unsigned int* __restrict__ hs,
                                                  const int2* __restrict__ ninfo,
                                                  const int* __restrict__ dense,
                                                  const float* __restrict__ dinv,
                                                  const float* __restrict__ bias,
                                                  unsigned int* __restrict__ out) {
    int node = blockIdx.x * 4 + (threadIdx.x >> 6);
    if (node >= N_NODES) return;
    int lane = threadIdx.x & 63;
    int2 gi = ninfo[node];
    int dbase = __builtin_amdgcn_readfirstlane(gi.x);
    int r8d   = __builtin_amdgcn_readfirstlane(gi.y);
    const int* row = dense + dbase;                // wave-uniform -> scalar loads
    const char* hb = (const char*)hs;
    int l4 = lane * 4;
    // hoisted epilogue operands
    float dn = dinv[node];
    unsigned int us = hs[(size_t)node * 64 + lane];    // self term
    float bx = bias[lane * 2], by = bias[lane * 2 + 1];
    float ax = 0.f, ay = 0.f;
    for (int e = 0; e < r8d; e += 8) {
        int o0 = row[e + 0], o1 = row[e + 1], o2 = row[e + 2], o3 = row[e + 3];
        int o4 = row[e + 4], o5 = row[e + 5], o6 = row[e + 6], o7 = row[e + 7];
        unsigned int u0 = *(const unsigned int*)(hb + (o0 + l4));
        unsigned int u1 = *(const unsigned int*)(hb + (o1 + l4));
        unsigned int u2 = *(const unsigned int*)(hb + (o2 + l4));
        unsigned int u3 = *(const unsigned int*)(hb + (o3 + l4));
        unsigned int u4 = *(const unsigned int*)(hb + (o4 + l4));
        unsigned int u5 = *(const unsigned int*)(hb + (o5 + l4));
        unsigned int u6 = *(const unsigned int*)(hb + (o6 + l4));
        unsigned int u7 = *(const unsigned int*)(hb + (o7 + l4));
        ax += ((bf_lo(u0) + bf_lo(u1)) + (bf_lo(u2) + bf_lo(u3)))
            + ((bf_lo(u4) + bf_lo(u5)) + (bf_lo(u6) + bf_lo(u7)));
        ay += ((bf_hi(u0) + bf_hi(u1)) + (bf_hi(u2) + bf_hi(u3)))
            + ((bf_hi(u4) + bf_hi(u5)) + (bf_hi(u6) + bf_hi(u7)));
    }
    float sx = ax + bf_lo(us), sy = ay + bf_hi(us);
    float ox = fmaxf(fmaf(sx, dn, bx), 0.f);
    float oy = fmaxf(fmaf(sy, dn, by), 0.f);
    // sliced write: slice = lane>>3, u32-in-slice = lane&7
    out[((size_t)(lane >> 3) * N_NODES + node) * 8 + (lane & 7)] = pk_bf16x2(ox, oy);
}

// ---- graph boundaries from sorted batch ----
__global__ void gptr_kernel(const int* __restrict__ batch, int* __restrict__ gptr) {
    int n = blockIdx.x * 256 + threadIdx.x;
    if (n >= N_NODES) return;
    int b1 = batch[n];
    if (n == 0) {
        for (int g = 0; g <= b1; ++g) gptr[g] = 0;
    } else {
        int b0 = batch[n - 1];
        for (int g = b0 + 1; g <= b1; ++g) gptr[g] = n;
    }
    if (n == N_NODES - 1) {
        for (int g = b1 + 1; g <= N_GRAPHS; ++g) gptr[g] = N_NODES;
    }
}

// ---- pooling + linear head (reads SLICED packed bf16 h) ----
__global__ __launch_bounds__(256) void pool_kernel(const unsigned int* __restrict__ h,
                                                   const int* __restrict__ gptr,
                                                   const float* __restrict__ lin_w,
                                                   const float* __restrict__ lin_b,
                                                   float* __restrict__ out) {
    __shared__ float part[4];
    int g = blockIdx.x;
    int s = gptr[g], epos = gptr[g + 1];
    int w = threadIdx.x >> 6, lane = threadIdx.x & 63;
    size_t sbase = (size_t)(lane >> 3) * N_NODES * 8 + (lane & 7);
    float2 wv = *(const float2*)(lin_w + lane * 2);
    float acc = 0.f;
    for (int n = s + w; n < epos; n += 4) {
        unsigned int u = h[sbase + (size_t)n * 8];
        acc += bf_lo(u) * wv.x + bf_hi(u) * wv.y;
    }
#pragma unroll
    for (int off = 32; off > 0; off >>= 1) acc += __shfl_down(acc, off, 64);
    if (lane == 0) part[w] = acc;
    __syncthreads();
    if (threadIdx.x == 0) {
        float t = (part[0] + part[1]) + (part[2] + part[3]);
        float c = (float)(epos - s);
        if (c < 1.f) c = 1.f;
        out[g] = t / c + lin_b[0];
    }
}

extern "C" void kernel_launch(void* const* d_in, const int* in_sizes, int n_in,
                              void* d_out, int out_size, void* d_ws, size_t ws_size,
                              hipStream_t stream) {
    const float* x       = (const float*)d_in[0];
    const int*   eidx    = (const int*)d_in[1];
    const int*   batch   = (const int*)d_in[2];
    const float* conv_w0 = (const float*)d_in[3];
    const float* conv_b0 = (const float*)d_in[4];
    const float* conv_ws = (const float*)d_in[5];
    const float* conv_bs = (const float*)d_in[6];
    const float* lin_w   = (const float*)d_in[7];
    const float* lin_b   = (const float*)d_in[8];
    const int* srcI = eidx;
    const int* dstI = eidx + N_EDGES;

    char* ws = (char*)d_ws;
    size_t off = 0;
    auto alloc = [&](size_t bytes) {
        void* p = ws + off;
        off += (bytes + 255) & ~(size_t)255;
        return p;
    };
    unsigned int*  xb      = (unsigned int*)alloc((size_t)N_NODES * 64 * 4);       // sliced
    unsigned int*  hsb     = (unsigned int*)alloc((size_t)(N_NODES + 1) * 64 * 4); // row-major + sentinel
    int*           dense   = (int*)alloc((size_t)(N_EDGES + 8 * N_NODES) * 4);
    int*           part    = (int*)alloc((size_t)NBUCK * BCAP * 4);
    int*           cnt     = (int*)alloc((size_t)N_NODES * 4);
    float*         dinv    = (float*)alloc((size_t)N_NODES * 4);
    int*           bcur    = (int*)alloc((size_t)(NBUCK + 1) * 4);  // +1: dense cursor
    int*           gptr    = (int*)alloc((size_t)(N_GRAPHS + 1) * 4);
    int2*          ninfo   = (int2*)alloc((size_t)N_NODES * 8);
    unsigned short* wt     = (unsigned short*)alloc((size_t)NLAYERS * DH * DH * 2);
    int* gcursor = bcur + NBUCK;
    (void)ws_size; (void)in_sizes; (void)n_in; (void)out_size;

    hipMemsetAsync(bcur, 0, (size_t)(NBUCK + 1) * 4, stream);

    binA_kernel<<<BLOCKS_A, 256, 0, stream>>>(srcI, dstI, bcur, part);
    binB_kernel<<<NBUCK, 256, 0, stream>>>(part, bcur, cnt, ninfo, gcursor, dense);
    dinv_kernel<<<(N_NODES + 255) / 256, 256, 0, stream>>>(cnt, dinv, hsb);
    gptr_kernel<<<(N_NODES + 255) / 256, 256, 0, stream>>>(batch, gptr);
    wconv_kernel<<<(NLAYERS * DH * DH + 255) / 256, 256, 0, stream>>>(conv_w0, conv_ws, wt);
    xconv_kernel<<<(N_NODES * 32 + 255) / 256, 256, 0, stream>>>(x, xb);

    for (int l = 0; l < NLAYERS; ++l) {
        const float* b = (l == 0) ? conv_b0 : conv_bs + (size_t)(l - 1) * DH;
        mfma_gemm_kernel<<<512, 512, 0, stream>>>(xb, wt + (size_t)l * DH * DH, dinv, hsb);
        agg_kernel<<<(N_NODES + 3) / 4, 256, 0, stream>>>(hsb, ninfo, dense, dinv, b, xb);
    }

    pool_kernel<<<N_GRAPHS, 256, 0, stream>>>(xb, gptr, lin_w, lin_b, (float*)d_out);
}

// Round 19
// 540.882 us; speedup vs baseline: 1.1194x; 1.0161x over previous
//
#include <hip/hip_runtime.h>

#define N_NODES 100000
#define N_EDGES 1600000
#define N_GRAPHS 512
#define DH 128
#define CAP 64             // per-node edge capacity (max in-deg ~42 for Poisson(16))
#define NLAYERS 6
#define NBUCK 196          // buckets of 512 nodes
#define BCAP 8960          // per-bucket edge capacity (mean 8163, +8 sigma)
#define CHUNK_A 4096
#define BLOCKS_A ((N_EDGES + CHUNK_A - 1) / CHUNK_A)   // 391
#define SENT_OFF (N_NODES << 8)      // sentinel byte-offset -> zero row at N_NODES
#define NT_TILES (N_NODES / 16)      // 6250
#define NPAIRS (NT_TILES / 2)        // 3125

typedef short bf16x8 __attribute__((ext_vector_type(8)));
typedef float f32x4 __attribute__((ext_vector_type(4)));

// ---- bf16 helpers (RNE) ----
__device__ inline unsigned int pk_bf16x2(float a, float b) {
    unsigned int ua = __float_as_uint(a), ub = __float_as_uint(b);
    ua += 0x7fffu + ((ua >> 16) & 1u);
    ub += 0x7fffu + ((ub >> 16) & 1u);
    return (ua >> 16) | (ub & 0xffff0000u);
}
__device__ inline unsigned short bf16_rne(float f) {
    unsigned int u = __float_as_uint(f);
    u += 0x7fffu + ((u >> 16) & 1u);
    return (unsigned short)(u >> 16);
}
__device__ inline float bf_lo(unsigned int u) { return __uint_as_float(u << 16); }
__device__ inline float bf_hi(unsigned int u) { return __uint_as_float(u & 0xffff0000u); }

// ---- Pass A: radix partition edges into NBUCK buckets (by dst>>9), packed ----
// entry = (src << 9) | (dst & 511); int4-vectorized reads (4 edges/thread/iter)
__global__ __launch_bounds__(256) void binA_kernel(const int* __restrict__ src,
                                                   const int* __restrict__ dst,
                                                   int* __restrict__ bcur,
                                                   int* __restrict__ part) {
    __shared__ int hist[NBUCK];
    __shared__ int base[NBUCK];
    int tid = threadIdx.x;
    int e0 = blockIdx.x * CHUNK_A;                 // CHUNK_A = 4096 = 256*4*4
    for (int b = tid; b < NBUCK; b += 256) hist[b] = 0;
    __syncthreads();
    // phase 1: histogram, 4 edges per int4
#pragma unroll
    for (int it = 0; it < 4; ++it) {
        int i = e0 + (it * 256 + tid) * 4;
        if (i < N_EDGES) {
            int4 d4 = *(const int4*)&dst[i];
            atomicAdd(&hist[d4.x >> 9], 1);
            atomicAdd(&hist[d4.y >> 9], 1);
            atomicAdd(&hist[d4.z >> 9], 1);
            atomicAdd(&hist[d4.w >> 9], 1);
        }
    }
    __syncthreads();
    for (int b = tid; b < NBUCK; b += 256) {
        base[b] = atomicAdd(&bcur[b], hist[b]);
        hist[b] = 0;                      // reuse as local cursor
    }
    __syncthreads();
    // phase 2: scatter, 4 edges per int4 pair
#pragma unroll
    for (int it = 0; it < 4; ++it) {
        int i = e0 + (it * 256 + tid) * 4;
        if (i < N_EDGES) {
            int4 s4 = *(const int4*)&src[i];
            int4 d4 = *(const int4*)&dst[i];
            int b0 = d4.x >> 9, b1 = d4.y >> 9, b2 = d4.z >> 9, b3 = d4.w >> 9;
            int p0 = base[b0] + atomicAdd(&hist[b0], 1);
            int p1 = base[b1] + atomicAdd(&hist[b1], 1);
            int p2 = base[b2] + atomicAdd(&hist[b2], 1);
            int p3 = base[b3] + atomicAdd(&hist[b3], 1);
            if (p0 < BCAP) part[(size_t)b0 * BCAP + p0] = (s4.x << 9) | (d4.x & 511);
            if (p1 < BCAP) part[(size_t)b1 * BCAP + p1] = (s4.y << 9) | (d4.y & 511);
            if (p2 < BCAP) part[(size_t)b2 * BCAP + p2] = (s4.z << 9) | (d4.z & 511);
            if (p3 < BCAP) part[(size_t)b3 * BCAP + p3] = (s4.w << 9) | (d4.w & 511);
        }
    }
}

// ---- Pass B: count part, compute per-node dense bases, then scatter part
// DIRECTLY into dense (no scratch round-trip); predicated sentinel fill.
// ninfo[n] = {dense base, round8(deg)}.
__global__ __launch_bounds__(256) void binB_kernel(const int* __restrict__ part,
                                                   const int* __restrict__ bcur,
                                                   int* __restrict__ cnt,
                                                   int2* __restrict__ ninfo,
                                                   int* __restrict__ gcursor,
                                                   int* __restrict__ dense) {
    __shared__ int lcnt[512];
    __shared__ int lcur[512];
    __shared__ int nbase[512];
    __shared__ int psum[64];
    __shared__ int bucket_base;
    int tid = threadIdx.x;
    int b = blockIdx.x;
    int node0 = b << 9;
    for (int i = tid; i < 512; i += 256) { lcnt[i] = 0; lcur[i] = 0; }
    __syncthreads();
    int m = bcur[b]; if (m > BCAP) m = BCAP;
    const int* p = part + (size_t)b * BCAP;
    // phase 1: per-node counts
    for (int i = tid; i < m; i += 256) {
        atomicAdd(&lcnt[p[i] & 511], 1);
    }
    __syncthreads();
    for (int i = tid; i < 512; i += 256) {
        int n = node0 + i;
        if (n < N_NODES) cnt[n] = lcnt[i];
    }
    if (tid < 64) {
        int acc = 0;
        int base = tid * 8;
#pragma unroll
        for (int i = 0; i < 8; ++i) {
            int dg = lcnt[base + i]; if (dg > CAP) dg = CAP;
            acc += (dg + 7) & ~7;
        }
        psum[tid] = acc;
    }
    __syncthreads();
    if (tid == 0) {
        int acc = 0;
        for (int i = 0; i < 64; ++i) { int t = psum[i]; psum[i] = acc; acc += t; }
        bucket_base = atomicAdd(gcursor, acc);
    }
    __syncthreads();
    if (tid < 64) {
        int off = psum[tid] + bucket_base;
        int base = tid * 8;
#pragma unroll
        for (int i = 0; i < 8; ++i) {
            int dg = lcnt[base + i]; if (dg > CAP) dg = CAP;
            nbase[base + i] = off;
            off += (dg + 7) & ~7;
        }
    }
    __syncthreads();
    for (int i = tid; i < 512; i += 256) {
        int n = node0 + i;
        if (n < N_NODES) {
            int dg = lcnt[i]; if (dg > CAP) dg = CAP;
            ninfo[n] = make_int2(nbase[i], (dg + 7) & ~7);
        }
    }
    // phase 2: scatter directly into dense
    for (int i = tid; i < m; i += 256) {
        int v = p[i];
        int dl = v & 511;
        int sv = (int)(((unsigned int)v) >> 9);
        int r = atomicAdd(&lcur[dl], 1);
        if (r < CAP) dense[nbase[dl] + r] = sv << 8;
    }
    __syncthreads();
    // sentinel fill: r8-dg < 8 always -> one predicated write per (node, slot)
    for (int nb = 0; nb < 512; nb += 32) {   // 32 nodes per round, 8 thr/node
        int nl = nb + (tid >> 3);
        int n = node0 + nl;
        if (n < N_NODES) {
            int dg = lcnt[nl]; if (dg > CAP) dg = CAP;
            int r8 = (dg + 7) & ~7;
            int e = dg + (tid & 7);
            if (e < r8) dense[nbase[nl] + e] = SENT_OFF;
        }
    }
}

// ---- fused prep: dinv + sentinel-row zero + graph boundaries ----
__global__ void prep_kernel(const int* __restrict__ cnt, float* __restrict__ dinv,
                            unsigned int* __restrict__ hsb,
                            const int* __restrict__ batch, int* __restrict__ gptr) {
    int n = blockIdx.x * 256 + threadIdx.x;
    if (n < 64) hsb[(size_t)N_NODES * 64 + n] = 0u;
    if (n >= N_NODES) return;
    dinv[n] = rsqrtf((float)(cnt[n] + 1));
    int b1 = batch[n];
    if (n == 0) {
        for (int g = 0; g <= b1; ++g) gptr[g] = 0;
    } else {
        int b0 = batch[n - 1];
        for (int g = b0 + 1; g <= b1; ++g) gptr[g] = n;
    }
    if (n == N_NODES - 1) {
        for (int g = b1 + 1; g <= N_GRAPHS; ++g) gptr[g] = N_NODES;
    }
}

// ---- W convert: WT[l][c][k] = bf16(W_l[k][c]) (transposed, plain RNE) ----
__global__ void wconv_kernel(const float* __restrict__ w0, const float* __restrict__ ws,
                             unsigned short* __restrict__ wt) {
    int i = blockIdx.x * 256 + threadIdx.x;
    if (i >= NLAYERS * DH * DH) return;
    int l = i >> 14;
    int r = i & 16383;
    int c = r >> 7, k = r & 127;
    const float* W = (l == 0) ? w0 : ws + (size_t)(l - 1) * DH * DH;
    wt[i] = bf16_rne(W[k * DH + c]);
}

// ---- x fp32 -> packed bf16x2, SLICE-MAJOR xb: xb[(cu>>3)*N + node][cu&7] ----
__global__ void xconv_kernel(const float* __restrict__ x, unsigned int* __restrict__ xb) {
    int i = blockIdx.x * 256 + threadIdx.x;       // one uint2 (4 floats) per thread
    if (i >= N_NODES * 32) return;
    float4 v = *(const float4*)&x[(size_t)i * 4];
    int node = i >> 5;
    int cu = (i & 31) * 2;
    int ss = cu >> 3, o = cu & 7;
    uint2 ov = make_uint2(pk_bf16x2(v.x, v.y), pk_bf16x2(v.z, v.w));
    *(uint2*)&xb[((size_t)ss * N_NODES + node) * 8 + o] = ov;
}

// ---- MFMA GEMM, PAIR-UNROLLED persistent loop with 1-deep prefetch ----
// Single bf16 W (no hi/lo split): 8 MFMAs per pair-iteration.
// Sliced B-loads (coalesced), ROW-MAJOR stores to hsb. grid = 512.
#define LOADB(v, kb, nd) \
    v = *(const bf16x8*)&Xb[(((size_t)(2*(kb) + (lk >> 1)) * N_NODES + (nd)) * 8) + (lk & 1) * 4];

__global__ __launch_bounds__(512) void mfma_gemm_kernel(const unsigned int* __restrict__ Xb,
                                                        const unsigned short* __restrict__ WT,
                                                        const float* __restrict__ dinv,
                                                        unsigned int* __restrict__ Yb) {
    int w = threadIdx.x >> 6;
    int lane = threadIdx.x & 63;
    int l15 = lane & 15, lk = lane >> 4;          // lk in 0..3
    int wc = w * 16 + l15;                        // A row (output dim)
    bf16x8 aw[4];
#pragma unroll
    for (int kb = 0; kb < 4; ++kb) {
        int k0 = kb * 32 + lk * 8;
        aw[kb] = *(const bf16x8*)&WT[wc * DH + k0];
    }
    int p = blockIdx.x;
    if (p >= NPAIRS) return;
    int nodeA = p * 32 + l15;
    int nodeB = nodeA + 16;
    bf16x8 a0, a1, a2, a3, b0, b1, b2, b3;
    LOADB(a0, 0, nodeA); LOADB(a1, 1, nodeA); LOADB(a2, 2, nodeA); LOADB(a3, 3, nodeA);
    LOADB(b0, 0, nodeB); LOADB(b1, 1, nodeB); LOADB(b2, 2, nodeB); LOADB(b3, 3, nodeB);
    for (;;) {
        int pn = p + gridDim.x;
        bool hn = pn < NPAIRS;
        int nodeAn = pn * 32 + l15;
        int nodeBn = nodeAn + 16;
        bf16x8 na0 = a0, na1 = a1, na2 = a2, na3 = a3;
        bf16x8 nb0 = b0, nb1 = b1, nb2 = b2, nb3 = b3;
        if (hn) {
            LOADB(na0, 0, nodeAn); LOADB(na1, 1, nodeAn); LOADB(na2, 2, nodeAn); LOADB(na3, 3, nodeAn);
            LOADB(nb0, 0, nodeBn); LOADB(nb1, 1, nodeBn); LOADB(nb2, 2, nodeBn); LOADB(nb3, 3, nodeBn);
        }
        float dnA = dinv[nodeA];
        float dnB = dinv[nodeB];
        f32x4 accA = {0.f, 0.f, 0.f, 0.f};
        f32x4 accB = {0.f, 0.f, 0.f, 0.f};
        accA = __builtin_amdgcn_mfma_f32_16x16x32_bf16(aw[0], a0, accA, 0, 0, 0);
        accB = __builtin_amdgcn_mfma_f32_16x16x32_bf16(aw[0], b0, accB, 0, 0, 0);
        accA = __builtin_amdgcn_mfma_f32_16x16x32_bf16(aw[1], a1, accA, 0, 0, 0);
        accB = __builtin_amdgcn_mfma_f32_16x16x32_bf16(aw[1], b1, accB, 0, 0, 0);
        accA = __builtin_amdgcn_mfma_f32_16x16x32_bf16(aw[2], a2, accA, 0, 0, 0);
        accB = __builtin_amdgcn_mfma_f32_16x16x32_bf16(aw[2], b2, accB, 0, 0, 0);
        accA = __builtin_amdgcn_mfma_f32_16x16x32_bf16(aw[3], a3, accA, 0, 0, 0);
        accB = __builtin_amdgcn_mfma_f32_16x16x32_bf16(aw[3], b3, accB, 0, 0, 0);
        uint2 ovA = make_uint2(pk_bf16x2(accA[0] * dnA, accA[1] * dnA),
                               pk_bf16x2(accA[2] * dnA, accA[3] * dnA));
        uint2 ovB = make_uint2(pk_bf16x2(accB[0] * dnB, accB[1] * dnB),
                               pk_bf16x2(accB[2] * dnB, accB[3] * dnB));
        *(uint2*)&Yb[(size_t)nodeA * 64 + w * 8 + lk * 2] = ovA;   // row-major
        *(uint2*)&Yb[(size_t)nodeB * 64 + w * 8 + lk * 2] = ovB;
        if (!hn) break;
        p = pn; nodeA = nodeAn; nodeB = nodeBn;
        a0 = na0; a1 = na1; a2 = na2; a3 = na3;
        b0 = nb0; b1 = nb1; b2 = nb2; b3 = nb3;
    }
}

// ---- aggregation: wave = 1 node, full-row gathers (256B/instr, 2 lines/edge),
// dense per-node sentinel-padded indices via SCALAR loads; SLICED output ----
__global__ __launch_bounds__(256) void agg_kernel(const unsigned int* __restrict__ hs,
                                                  const int2* __restrict__ ninfo,
                                                  const int* __restrict__ dense,
                                                  const float* __restrict__ dinv,
                                                  const float* __restrict__ bias,
                                                  unsigned int* __restrict__ out) {
    int node = blockIdx.x * 4 + (threadIdx.x >> 6);
    if (node >= N_NODES) return;
    int lane = threadIdx.x & 63;
    int2 gi = ninfo[node];
    int dbase = __builtin_amdgcn_readfirstlane(gi.x);
    int r8d   = __builtin_amdgcn_readfirstlane(gi.y);
    const int* row = dense + dbase;                // wave-uniform -> scalar loads
    const char* hb = (const char*)hs;
    int l4 = lane * 4;
    // hoisted epilogue operands
    float dn = dinv[node];
    unsigned int us = hs[(size_t)node * 64 + lane];    // self term
    float bx = bias[lane * 2], by = bias[lane * 2 + 1];
    float ax = 0.f, ay = 0.f;
    for (int e = 0; e < r8d; e += 8) {
        int o0 = row[e + 0], o1 = row[e + 1], o2 = row[e + 2], o3 = row[e + 3];
        int o4 = row[e + 4], o5 = row[e + 5], o6 = row[e + 6], o7 = row[e + 7];
        unsigned int u0 = *(const unsigned int*)(hb + (o0 + l4));
        unsigned int u1 = *(const unsigned int*)(hb + (o1 + l4));
        unsigned int u2 = *(const unsigned int*)(hb + (o2 + l4));
        unsigned int u3 = *(const unsigned int*)(hb + (o3 + l4));
        unsigned int u4 = *(const unsigned int*)(hb + (o4 + l4));
        unsigned int u5 = *(const unsigned int*)(hb + (o5 + l4));
        unsigned int u6 = *(const unsigned int*)(hb + (o6 + l4));
        unsigned int u7 = *(const unsigned int*)(hb + (o7 + l4));
        ax += ((bf_lo(u0) + bf_lo(u1)) + (bf_lo(u2) + bf_lo(u3)))
            + ((bf_lo(u4) + bf_lo(u5)) + (bf_lo(u6) + bf_lo(u7)));
        ay += ((bf_hi(u0) + bf_hi(u1)) + (bf_hi(u2) + bf_hi(u3)))
            + ((bf_hi(u4) + bf_hi(u5)) + (bf_hi(u6) + bf_hi(u7)));
    }
    float sx = ax + bf_lo(us), sy = ay + bf_hi(us);
    float ox = fmaxf(fmaf(sx, dn, bx), 0.f);
    float oy = fmaxf(fmaf(sy, dn, by), 0.f);
    // sliced write: slice = lane>>3, u32-in-slice = lane&7
    out[((size_t)(lane >> 3) * N_NODES + node) * 8 + (lane & 7)] = pk_bf16x2(ox, oy);
}

// ---- pooling + linear head (reads SLICED packed bf16 h) ----
__global__ __launch_bounds__(256) void pool_kernel(const unsigned int* __restrict__ h,
                                                   const int* __restrict__ gptr,
                                                   const float* __restrict__ lin_w,
                                                   const float* __restrict__ lin_b,
                                                   float* __restrict__ out) {
    __shared__ float part[4];
    int g = blockIdx.x;
    int s = gptr[g], epos = gptr[g + 1];
    int w = threadIdx.x >> 6, lane = threadIdx.x & 63;
    size_t sbase = (size_t)(lane >> 3) * N_NODES * 8 + (lane & 7);
    float2 wv = *(const float2*)(lin_w + lane * 2);
    float acc = 0.f;
    for (int n = s + w; n < epos; n += 4) {
        unsigned int u = h[sbase + (size_t)n * 8];
        acc += bf_lo(u) * wv.x + bf_hi(u) * wv.y;
    }
#pragma unroll
    for (int off = 32; off > 0; off >>= 1) acc += __shfl_down(acc, off, 64);
    if (lane == 0) part[w] = acc;
    __syncthreads();
    if (threadIdx.x == 0) {
        float t = (part[0] + part[1]) + (part[2] + part[3]);
        float c = (float)(epos - s);
        if (c < 1.f) c = 1.f;
        out[g] = t / c + lin_b[0];
    }
}

extern "C" void kernel_launch(void* const* d_in, const int* in_sizes, int n_in,
                              void* d_out, int out_size, void* d_ws, size_t ws_size,
                              hipStream_t stream) {
    const float* x       = (const float*)d_in[0];
    const int*   eidx    = (const int*)d_in[1];
    const int*   batch   = (const int*)d_in[2];
    const float* conv_w0 = (const float*)d_in[3];
    const float* conv_b0 = (const float*)d_in[4];
    const float* conv_ws = (const float*)d_in[5];
    const float* conv_bs = (const float*)d_in[6];
    const float* lin_w   = (const float*)d_in[7];
    const float* lin_b   = (const float*)d_in[8];
    const int* srcI = eidx;
    const int* dstI = eidx + N_EDGES;

    char* ws = (char*)d_ws;
    size_t off = 0;
    auto alloc = [&](size_t bytes) {
        void* p = ws + off;
        off += (bytes + 255) & ~(size_t)255;
        return p;
    };
    unsigned int*  xb      = (unsigned int*)alloc((size_t)N_NODES * 64 * 4);       // sliced
    unsigned int*  hsb     = (unsigned int*)alloc((size_t)(N_NODES + 1) * 64 * 4); // row-major + sentinel
    int*           dense   = (int*)alloc((size_t)(N_EDGES + 8 * N_NODES) * 4);
    int*           part    = (int*)alloc((size_t)NBUCK * BCAP * 4);
    int*           cnt     = (int*)alloc((size_t)N_NODES * 4);
    float*         dinv    = (float*)alloc((size_t)N_NODES * 4);
    int*           bcur    = (int*)alloc((size_t)(NBUCK + 1) * 4);  // +1: dense cursor
    int*           gptr    = (int*)alloc((size_t)(N_GRAPHS + 1) * 4);
    int2*          ninfo   = (int2*)alloc((size_t)N_NODES * 8);
    unsigned short* wt     = (unsigned short*)alloc((size_t)NLAYERS * DH * DH * 2);
    int* gcursor = bcur + NBUCK;
    (void)ws_size; (void)in_sizes; (void)n_in; (void)out_size;

    hipMemsetAsync(bcur, 0, (size_t)(NBUCK + 1) * 4, stream);

    binA_kernel<<<BLOCKS_A, 256, 0, stream>>>(srcI, dstI, bcur, part);
    binB_kernel<<<NBUCK, 256, 0, stream>>>(part, bcur, cnt, ninfo, gcursor, dense);
    prep_kernel<<<(N_NODES + 255) / 256, 256, 0, stream>>>(cnt, dinv, hsb, batch, gptr);
    wconv_kernel<<<(NLAYERS * DH * DH + 255) / 256, 256, 0, stream>>>(conv_w0, conv_ws, wt);
    xconv_kernel<<<(N_NODES * 32 + 255) / 256, 256, 0, stream>>>(x, xb);

    for (int l = 0; l < NLAYERS; ++l) {
        const float* b = (l == 0) ? conv_b0 : conv_bs + (size_t)(l - 1) * DH;
        mfma_gemm_kernel<<<512, 512, 0, stream>>>(xb, wt + (size_t)l * DH * DH, dinv, hsb);
        agg_kernel<<<(N_NODES + 3) / 4, 256, 0, stream>>>(hsb, ninfo, dense, dinv, b, xb);
    }

    pool_kernel<<<N_GRAPHS, 256, 0, stream>>>(xb, gptr, lin_w, lin_b, (float*)d_out);
}